// Round 1
// baseline (958.800 us; speedup 1.0000x reference)
//
#include <hip/hip_runtime.h>

#define B_ 8
#define K_ 4096
#define IN_ 512
#define H_ 8
#define D_ 64
#define HD_ 512  // H_*D_

// ws layout (floats):
//   G    [B_][IN_][IN_]    off 0        len 2097152
//   Aall [H*B][D_][IN_]    off 2097152  len 2097152   A = Wq_h^T @ G_b
//   Wfin [H*B][IN_][D_]    off 4194304  len 2097152
//   bfin [H*B][D_]         off 6291456  len 4096
//   svec [B_][IN_]         off 6295552  len 4096      column sums of X_b

// ---------------- G_b = X_b^T X_b  (+ column sums on diagonal blocks) ----
__global__ __launch_bounds__(256) void k_gram(const float* __restrict__ x,
                                              float* __restrict__ G,
                                              float* __restrict__ svec) {
  const int it = blockIdx.x, jt = blockIdx.y, b = blockIdx.z;
  if (jt < it) return;  // symmetric: compute upper triangle, mirror on write
  __shared__ float Xi[16][64];
  __shared__ float Xj[16][64];
  const float* Xb = x + (size_t)b * K_ * IN_;
  const int tx = threadIdx.x, ty = threadIdx.y;
  const int tid = ty * 16 + tx;
  const int i0 = it * 64, j0 = jt * 64;
  const bool diag = (it == jt);
  float acc[4][4] = {};
  float ssum = 0.f;
  for (int k0 = 0; k0 < K_; k0 += 16) {
#pragma unroll
    for (int r = 0; r < 4; ++r) {
      int idx = tid + 256 * r;
      int kk = idx >> 6, cc = idx & 63;
      const float* row = Xb + (size_t)(k0 + kk) * IN_;
      Xi[kk][cc] = row[i0 + cc];
      Xj[kk][cc] = row[j0 + cc];
    }
    __syncthreads();
#pragma unroll
    for (int kk = 0; kk < 16; ++kk) {
      float a[4], bb[4];
#pragma unroll
      for (int u = 0; u < 4; ++u) a[u] = Xi[kk][ty * 4 + u];
#pragma unroll
      for (int u = 0; u < 4; ++u) bb[u] = Xj[kk][tx * 4 + u];
#pragma unroll
      for (int u = 0; u < 4; ++u)
#pragma unroll
        for (int w = 0; w < 4; ++w) acc[u][w] += a[u] * bb[w];
    }
    if (diag && tid < 64) {
#pragma unroll
      for (int kk = 0; kk < 16; ++kk) ssum += Xi[kk][tid];
    }
    __syncthreads();
  }
  float* Gb = G + (size_t)b * IN_ * IN_;
#pragma unroll
  for (int u = 0; u < 4; ++u)
#pragma unroll
    for (int w = 0; w < 4; ++w) {
      int gi = i0 + ty * 4 + u, gj = j0 + tx * 4 + w;
      Gb[(size_t)gi * IN_ + gj] = acc[u][w];
      if (!diag) Gb[(size_t)gj * IN_ + gi] = acc[u][w];
    }
  if (diag && tid < 64) svec[b * IN_ + i0 + tid] = ssum;
}

// ---------------- Aall[h,b] = Wq_h^T (64x512) @ G_b (512x512) ------------
__global__ __launch_bounds__(256) void k_aall(const float* __restrict__ Wq,
                                              const float* __restrict__ G,
                                              float* __restrict__ Aall) {
  const int jt = blockIdx.x;  // c-tile of 64 within 512
  const int h = blockIdx.y, b = blockIdx.z;
  __shared__ float Ws[16][64];
  __shared__ float Gs[16][64];
  const float* Gb = G + (size_t)b * IN_ * IN_;
  const int tx = threadIdx.x, ty = threadIdx.y;
  const int tid = ty * 16 + tx;
  float acc[4][4] = {};
  for (int c0 = 0; c0 < IN_; c0 += 16) {
#pragma unroll
    for (int r = 0; r < 4; ++r) {
      int idx = tid + 256 * r;
      int kk = idx >> 6, cc = idx & 63;
      Ws[kk][cc] = Wq[(size_t)(c0 + kk) * HD_ + h * D_ + cc];
      Gs[kk][cc] = Gb[(size_t)(c0 + kk) * IN_ + jt * 64 + cc];
    }
    __syncthreads();
#pragma unroll
    for (int kk = 0; kk < 16; ++kk) {
      float a[4], bb[4];
#pragma unroll
      for (int u = 0; u < 4; ++u) a[u] = Ws[kk][ty * 4 + u];
#pragma unroll
      for (int u = 0; u < 4; ++u) bb[u] = Gs[kk][tx * 4 + u];
#pragma unroll
      for (int u = 0; u < 4; ++u)
#pragma unroll
        for (int w = 0; w < 4; ++w) acc[u][w] += a[u] * bb[w];
    }
    __syncthreads();
  }
  const int hb = h * B_ + b;
  float* Ahb = Aall + (size_t)hb * D_ * IN_;
#pragma unroll
  for (int u = 0; u < 4; ++u)
#pragma unroll
    for (int w = 0; w < 4; ++w)
      Ahb[(size_t)(ty * 4 + u) * IN_ + jt * 64 + tx * 4 + w] = acc[u][w];
}

// ------- per (h,b): E = A @ Wk_h, softmax, Wfin = (g*Wv_h@attn^T + Wp)/(1+g)
__global__ __launch_bounds__(256) void k_attn(
    const float* __restrict__ Wq, const float* __restrict__ Wk,
    const float* __restrict__ Wv, const float* __restrict__ Wp,
    const float* __restrict__ bq, const float* __restrict__ bk,
    const float* __restrict__ bv, const float* __restrict__ gamma,
    const float* __restrict__ Aall, const float* __restrict__ svec,
    float* __restrict__ Wfin, float* __restrict__ bfin) {
  const int h = blockIdx.x, b = blockIdx.y;
  const int hb = h * B_ + b;
  const int tx = threadIdx.x, ty = threadIdx.y;
  const int tid = ty * 16 + tx;
  __shared__ float Ast[64][17];
  __shared__ float Ws[16][64];
  __shared__ float Esh[64][65];
  __shared__ float t1[64], t2[64];
  const float* Ahb = Aall + (size_t)hb * D_ * IN_;

  // bias helpers: t1[e] = s.Wk_h[:,e], t2[d] = s.Wq_h[:,d]
  if (tid < 64) {
    float a2 = 0.f;
    for (int c = 0; c < IN_; ++c)
      a2 += svec[b * IN_ + c] * Wk[(size_t)c * HD_ + h * D_ + tid];
    t1[tid] = a2;
  } else if (tid < 128) {
    int d = tid - 64;
    float a2 = 0.f;
    for (int c = 0; c < IN_; ++c)
      a2 += svec[b * IN_ + c] * Wq[(size_t)c * HD_ + h * D_ + d];
    t2[d] = a2;
  }

  // E (64x64) = A (64x512) @ Wk_h (512x64)
  float acc[4][4] = {};
  for (int c0 = 0; c0 < IN_; c0 += 16) {
#pragma unroll
    for (int r = 0; r < 4; ++r) {
      int idx = tid + 256 * r;
      int dd = idx >> 4, kk = idx & 15;
      Ast[dd][kk] = Ahb[(size_t)dd * IN_ + c0 + kk];
      int kk2 = idx >> 6, ee = idx & 63;
      Ws[kk2][ee] = Wk[(size_t)(c0 + kk2) * HD_ + h * D_ + ee];
    }
    __syncthreads();
#pragma unroll
    for (int kk = 0; kk < 16; ++kk) {
      float a[4], bb[4];
#pragma unroll
      for (int u = 0; u < 4; ++u) a[u] = Ast[ty * 4 + u][kk];
#pragma unroll
      for (int u = 0; u < 4; ++u) bb[u] = Ws[kk][tx * 4 + u];
#pragma unroll
      for (int u = 0; u < 4; ++u)
#pragma unroll
        for (int w = 0; w < 4; ++w) acc[u][w] += a[u] * bb[w];
    }
    __syncthreads();
  }
  // write E with Q/K bias terms
#pragma unroll
  for (int u = 0; u < 4; ++u) {
    int d = ty * 4 + u;
    float bqd = bq[h * D_ + d];
    float t2d = t2[d];
#pragma unroll
    for (int w = 0; w < 4; ++w) {
      int e = tx * 4 + w;
      float bke = bk[h * D_ + e];
      Esh[d][e] = acc[u][w] + bqd * t1[e] + t2d * bke + (float)K_ * bqd * bke;
    }
  }
  __syncthreads();
  // softmax over e for each row d
  if (tid < 64) {
    float m = -1e30f;
    for (int e = 0; e < 64; ++e) m = fmaxf(m, Esh[tid][e]);
    float ssum = 0.f;
    for (int e = 0; e < 64; ++e) {
      float p = __expf(Esh[tid][e] - m);
      Esh[tid][e] = p;
      ssum += p;
    }
    float inv = 1.f / ssum;
    for (int e = 0; e < 64; ++e) Esh[tid][e] *= inv;
  }
  __syncthreads();
  const float g = gamma[h];
  const float inv1g = 1.f / (1.f + g);
  if (tid < 64) {
    float a2 = 0.f;
    for (int e = 0; e < 64; ++e) a2 += bv[h * D_ + e] * Esh[tid][e];
    bfin[hb * D_ + tid] = g * a2 * inv1g;
  }
  // Wfin[c][q] = (g * sum_e Wv_h[c,e]*attn[q,e] + Wp[c,q]) / (1+g)
  float* Wf = Wfin + (size_t)hb * IN_ * D_;
  for (int it2 = 0; it2 < 128; ++it2) {
    int idx = tid + 256 * it2;
    int c = idx >> 6, q = idx & 63;
    const float* Wvr = Wv + (size_t)c * HD_ + h * D_;
    float a2 = 0.f;
#pragma unroll
    for (int e = 0; e < 64; ++e) a2 += Wvr[e] * Esh[q][e];
    Wf[idx] = (g * a2 + Wp[(size_t)c * D_ + q]) * inv1g;
  }
}

// ---------------- Out[b,h,k0:k0+64,:] = Y_b @ Wfin[h,b] + bfin -----------
__global__ __launch_bounds__(256) void k_out(const float* __restrict__ y,
                                             const float* __restrict__ Wfin,
                                             const float* __restrict__ bfin,
                                             float* __restrict__ out) {
  const int kt = blockIdx.x;  // 0..63
  const int hb = blockIdx.y;  // h*8+b
  const int h = hb >> 3, b = hb & 7;
  __shared__ float Ys[64][17];
  __shared__ float Ws[16][64];
  const int tx = threadIdx.x, ty = threadIdx.y;
  const int tid = ty * 16 + tx;
  const float* Yb = y + (size_t)b * K_ * IN_;
  const float* Wf = Wfin + (size_t)hb * IN_ * D_;
  const int k0 = kt * 64;
  float acc[4][4] = {};
  for (int c0 = 0; c0 < IN_; c0 += 16) {
#pragma unroll
    for (int r = 0; r < 4; ++r) {
      int idx = tid + 256 * r;
      int rr = idx >> 4, kk = idx & 15;
      Ys[rr][kk] = Yb[(size_t)(k0 + rr) * IN_ + c0 + kk];
      int kk2 = idx >> 6, qq = idx & 63;
      Ws[kk2][qq] = Wf[(size_t)(c0 + kk2) * D_ + qq];
    }
    __syncthreads();
#pragma unroll
    for (int kk = 0; kk < 16; ++kk) {
      float a[4], bb[4];
#pragma unroll
      for (int u = 0; u < 4; ++u) a[u] = Ys[ty * 4 + u][kk];
#pragma unroll
      for (int u = 0; u < 4; ++u) bb[u] = Ws[kk][tx * 4 + u];
#pragma unroll
      for (int u = 0; u < 4; ++u)
#pragma unroll
        for (int w = 0; w < 4; ++w) acc[u][w] += a[u] * bb[w];
    }
    __syncthreads();
  }
  float* ob = out + (((size_t)b * H_ + h) * K_ + k0) * D_;
#pragma unroll
  for (int u = 0; u < 4; ++u) {
    int k = ty * 4 + u;
#pragma unroll
    for (int w = 0; w < 4; ++w) {
      int q = tx * 4 + w;
      ob[(size_t)k * D_ + q] = acc[u][w] + bfin[hb * D_ + q];
    }
  }
}

extern "C" void kernel_launch(void* const* d_in, const int* in_sizes, int n_in,
                              void* d_out, int out_size, void* d_ws,
                              size_t ws_size, hipStream_t stream) {
  const float* x = (const float*)d_in[0];
  const float* y = (const float*)d_in[1];
  const float* Wq = (const float*)d_in[2];
  const float* bq = (const float*)d_in[3];
  const float* Wk = (const float*)d_in[4];
  const float* bk = (const float*)d_in[5];
  const float* Wv = (const float*)d_in[6];
  const float* bv = (const float*)d_in[7];
  const float* Wp = (const float*)d_in[8];
  const float* gm = (const float*)d_in[9];
  float* out = (float*)d_out;
  float* ws = (float*)d_ws;

  float* G = ws;
  float* Aall = ws + 2097152;
  float* Wfin = ws + 4194304;
  float* bfin = ws + 6291456;
  float* svec = ws + 6295552;

  dim3 blk(16, 16);
  k_gram<<<dim3(8, 8, 8), blk, 0, stream>>>(x, G, svec);
  k_aall<<<dim3(8, 8, 8), blk, 0, stream>>>(Wq, G, Aall);
  k_attn<<<dim3(8, 8), blk, 0, stream>>>(Wq, Wk, Wv, Wp, bq, bk, bv, gm, Aall,
                                         svec, Wfin, bfin);
  k_out<<<dim3(64, 64), blk, 0, stream>>>(y, Wfin, bfin, out);
}

// Round 2
// 428.202 us; speedup vs baseline: 2.2391x; 2.2391x over previous
//
#include <hip/hip_runtime.h>

#define B_ 8
#define K_ 4096
#define IN_ 512
#define H_ 8
#define D_ 64
#define HD_ 512  // H_*D_

typedef short bf16x8 __attribute__((ext_vector_type(8)));
typedef float f32x4 __attribute__((ext_vector_type(4)));
typedef unsigned short u16;
typedef unsigned short us8v __attribute__((ext_vector_type(8)));

__device__ inline u16 f2bf_rn(float f) {
  unsigned u = __float_as_uint(f);
  u += 0x7fffu + ((u >> 16) & 1u);
  return (u16)(u >> 16);
}
__device__ inline float bf2f(u16 h) {
  return __uint_as_float(((unsigned)h) << 16);
}

// =========================================================================
// MFMA fast path
// ws layout (bytes):
//   xt_hi [B][IN][K] bf16   off 0
//   xt_lo [B][IN][K] bf16   off 33554432
//   y_bf  [B][K][IN] bf16   off 67108864
//   G     [B][IN][IN] f32   off 100663296
//   Aall  [64][D][IN] f32   off 109051904
//   Wft   [64][D][IN] bf16  off 117440512   (transposed Wfin, c contiguous)
//   attn  [64][D][D] f32    off 121634816
//   bfin  [64][D] f32       off 122683392
//   svec  [B][IN] f32       off 122699776
//   end 122716160
// =========================================================================

// x (B,K,IN) f32 -> xt_hi/xt_lo (B,IN,K) bf16 split, + column sums (atomic)
__global__ __launch_bounds__(256) void k_cvt_x(const float* __restrict__ x,
                                               u16* __restrict__ xt_hi,
                                               u16* __restrict__ xt_lo,
                                               float* __restrict__ svec) {
  const int kt = blockIdx.x, ct = blockIdx.y, b = blockIdx.z;
  __shared__ float Xs[64][65];
  const int tid = threadIdx.x;
  const float* src = x + ((size_t)b * K_ + kt * 64) * IN_ + ct * 64;
#pragma unroll
  for (int r = 0; r < 4; ++r) {
    int idx = tid + 256 * r;  // 0..1023
    int k = idx >> 4, c4 = (idx & 15) * 4;
    f32x4 v = *(const f32x4*)(src + (size_t)k * IN_ + c4);
    Xs[k][c4 + 0] = v[0];
    Xs[k][c4 + 1] = v[1];
    Xs[k][c4 + 2] = v[2];
    Xs[k][c4 + 3] = v[3];
  }
  __syncthreads();
  if (tid < 64) {
    float s = 0.f;
#pragma unroll
    for (int k = 0; k < 64; ++k) s += Xs[k][tid];
    atomicAdd(&svec[b * IN_ + ct * 64 + tid], s);
  }
#pragma unroll
  for (int r = 0; r < 2; ++r) {
    int idx = tid + 256 * r;  // 0..511
    int c = idx >> 3, ck = (idx & 7) * 8;
    us8v hv, lv;
#pragma unroll
    for (int j = 0; j < 8; ++j) {
      float f = Xs[ck + j][c];
      u16 h = f2bf_rn(f);
      float lo = f - bf2f(h);
      hv[j] = h;
      lv[j] = f2bf_rn(lo);
    }
    size_t off = ((size_t)(b * IN_ + ct * 64 + c)) * K_ + kt * 64 + ck;
    *(us8v*)(xt_hi + off) = hv;
    *(us8v*)(xt_lo + off) = lv;
  }
}

// y (B,K,IN) f32 -> y_bf bf16 (same layout)
__global__ __launch_bounds__(256) void k_cvt_y(const float* __restrict__ y,
                                               u16* __restrict__ y_bf) {
  size_t i = ((size_t)blockIdx.x * 256 + threadIdx.x) * 8;
  f32x4 a = *(const f32x4*)(y + i);
  f32x4 b = *(const f32x4*)(y + i + 4);
  us8v o;
  o[0] = f2bf_rn(a[0]); o[1] = f2bf_rn(a[1]);
  o[2] = f2bf_rn(a[2]); o[3] = f2bf_rn(a[3]);
  o[4] = f2bf_rn(b[0]); o[5] = f2bf_rn(b[1]);
  o[6] = f2bf_rn(b[2]); o[7] = f2bf_rn(b[3]);
  *(us8v*)(y_bf + i) = o;
}

#define GP 72  // padded LDS row (64 bf16 + 8) = 144 B: 16B-aligned, 2-way banks

// G_b = X^T X via bf16x3 MFMA. Block tile 64x64, upper triangle + mirror.
__global__ __launch_bounds__(256) void k_gram_mfma(
    const u16* __restrict__ xt_hi, const u16* __restrict__ xt_lo,
    float* __restrict__ G) {
  const int it = blockIdx.x, jt = blockIdx.y, b = blockIdx.z;
  if (jt < it) return;
  __shared__ u16 Pih[64 * GP], Pil[64 * GP], Pjh[64 * GP], Pjl[64 * GP];
  const int tid = threadIdx.x;
  const int wave = tid >> 6, lane = tid & 63;
  const int m16 = lane & 15, quad = lane >> 4;
  const size_t base_i = ((size_t)(b * IN_ + it * 64)) * K_;
  const size_t base_j = ((size_t)(b * IN_ + jt * 64)) * K_;
  f32x4 zf = {0.f, 0.f, 0.f, 0.f};
  f32x4 acc[4] = {zf, zf, zf, zf};
  for (int k0 = 0; k0 < K_; k0 += 64) {
    __syncthreads();
#pragma unroll
    for (int r = 0; r < 2; ++r) {
      int idx = tid + 256 * r;  // 0..511
      int row = idx >> 3, ck = (idx & 7) * 8;
      size_t gi = base_i + (size_t)row * K_ + k0 + ck;
      size_t gj = base_j + (size_t)row * K_ + k0 + ck;
      int lo = row * GP + ck;
      *(us8v*)&Pih[lo] = *(const us8v*)(xt_hi + gi);
      *(us8v*)&Pil[lo] = *(const us8v*)(xt_lo + gi);
      *(us8v*)&Pjh[lo] = *(const us8v*)(xt_hi + gj);
      *(us8v*)&Pjl[lo] = *(const us8v*)(xt_lo + gj);
    }
    __syncthreads();
#pragma unroll
    for (int kk = 0; kk < 64; kk += 32) {
      int arow = (wave * 16 + m16) * GP + kk + quad * 8;
      bf16x8 ah = *(const bf16x8*)&Pih[arow];
      bf16x8 al = *(const bf16x8*)&Pil[arow];
#pragma unroll
      for (int n = 0; n < 4; ++n) {
        int brow = (n * 16 + m16) * GP + kk + quad * 8;
        bf16x8 bh = *(const bf16x8*)&Pjh[brow];
        bf16x8 bl = *(const bf16x8*)&Pjl[brow];
        acc[n] = __builtin_amdgcn_mfma_f32_16x16x32_bf16(ah, bh, acc[n], 0, 0, 0);
        acc[n] = __builtin_amdgcn_mfma_f32_16x16x32_bf16(ah, bl, acc[n], 0, 0, 0);
        acc[n] = __builtin_amdgcn_mfma_f32_16x16x32_bf16(al, bh, acc[n], 0, 0, 0);
      }
    }
  }
  float* Gb = G + (size_t)b * IN_ * IN_;
  const bool diag = (it == jt);
#pragma unroll
  for (int n = 0; n < 4; ++n) {
#pragma unroll
    for (int r = 0; r < 4; ++r) {
      int gi = it * 64 + wave * 16 + quad * 4 + r;
      int gj = jt * 64 + n * 16 + m16;
      float v = acc[n][r];
      Gb[(size_t)gi * IN_ + gj] = v;
      if (!diag) Gb[(size_t)gj * IN_ + gi] = v;
    }
  }
}

// Aall[h,b] = Wq_h^T (64x512) @ G_b (512x512)  [f32 vector — small]
__global__ __launch_bounds__(256) void k_aall(const float* __restrict__ Wq,
                                              const float* __restrict__ G,
                                              float* __restrict__ Aall) {
  const int jt = blockIdx.x;
  const int h = blockIdx.y, b = blockIdx.z;
  __shared__ float Ws[16][64];
  __shared__ float Gs[16][64];
  const float* Gb = G + (size_t)b * IN_ * IN_;
  const int tx = threadIdx.x, ty = threadIdx.y;
  const int tid = ty * 16 + tx;
  float acc[4][4] = {};
  for (int c0 = 0; c0 < IN_; c0 += 16) {
#pragma unroll
    for (int r = 0; r < 4; ++r) {
      int idx = tid + 256 * r;
      int kk = idx >> 6, cc = idx & 63;
      Ws[kk][cc] = Wq[(size_t)(c0 + kk) * HD_ + h * D_ + cc];
      Gs[kk][cc] = Gb[(size_t)(c0 + kk) * IN_ + jt * 64 + cc];
    }
    __syncthreads();
#pragma unroll
    for (int kk = 0; kk < 16; ++kk) {
      float a[4], bb[4];
#pragma unroll
      for (int u = 0; u < 4; ++u) a[u] = Ws[kk][ty * 4 + u];
#pragma unroll
      for (int u = 0; u < 4; ++u) bb[u] = Gs[kk][tx * 4 + u];
#pragma unroll
      for (int u = 0; u < 4; ++u)
#pragma unroll
        for (int w = 0; w < 4; ++w) acc[u][w] += a[u] * bb[w];
    }
    __syncthreads();
  }
  const int hb = h * B_ + b;
  float* Ahb = Aall + (size_t)hb * D_ * IN_;
#pragma unroll
  for (int u = 0; u < 4; ++u)
#pragma unroll
    for (int w = 0; w < 4; ++w)
      Ahb[(size_t)(ty * 4 + u) * IN_ + jt * 64 + tx * 4 + w] = acc[u][w];
}

// per (h,b): E = A @ Wk_h (+bias terms), softmax -> attn (global), bfin
__global__ __launch_bounds__(256) void k_attn2(
    const float* __restrict__ Wq, const float* __restrict__ Wk,
    const float* __restrict__ bq, const float* __restrict__ bk,
    const float* __restrict__ bv, const float* __restrict__ gamma,
    const float* __restrict__ Aall, const float* __restrict__ svec,
    float* __restrict__ attn, float* __restrict__ bfin) {
  const int h = blockIdx.x, b = blockIdx.y;
  const int hb = h * B_ + b;
  const int tx = threadIdx.x, ty = threadIdx.y;
  const int tid = ty * 16 + tx;
  __shared__ float Ast[64][17];
  __shared__ float Ws[16][64];
  __shared__ float Esh[64][65];
  __shared__ float t1[64], t2[64];
  const float* Ahb = Aall + (size_t)hb * D_ * IN_;

  if (tid < 64) {
    float a2 = 0.f;
    for (int c = 0; c < IN_; ++c)
      a2 += svec[b * IN_ + c] * Wk[(size_t)c * HD_ + h * D_ + tid];
    t1[tid] = a2;
  } else if (tid < 128) {
    int d = tid - 64;
    float a2 = 0.f;
    for (int c = 0; c < IN_; ++c)
      a2 += svec[b * IN_ + c] * Wq[(size_t)c * HD_ + h * D_ + d];
    t2[d] = a2;
  }

  float acc[4][4] = {};
  for (int c0 = 0; c0 < IN_; c0 += 16) {
#pragma unroll
    for (int r = 0; r < 4; ++r) {
      int idx = tid + 256 * r;
      int dd = idx >> 4, kk = idx & 15;
      Ast[dd][kk] = Ahb[(size_t)dd * IN_ + c0 + kk];
      int kk2 = idx >> 6, ee = idx & 63;
      Ws[kk2][ee] = Wk[(size_t)(c0 + kk2) * HD_ + h * D_ + ee];
    }
    __syncthreads();
#pragma unroll
    for (int kk = 0; kk < 16; ++kk) {
      float a[4], bb[4];
#pragma unroll
      for (int u = 0; u < 4; ++u) a[u] = Ast[ty * 4 + u][kk];
#pragma unroll
      for (int u = 0; u < 4; ++u) bb[u] = Ws[kk][tx * 4 + u];
#pragma unroll
      for (int u = 0; u < 4; ++u)
#pragma unroll
        for (int w = 0; w < 4; ++w) acc[u][w] += a[u] * bb[w];
    }
    __syncthreads();
  }
#pragma unroll
  for (int u = 0; u < 4; ++u) {
    int d = ty * 4 + u;
    float bqd = bq[h * D_ + d];
    float t2d = t2[d];
#pragma unroll
    for (int w = 0; w < 4; ++w) {
      int e = tx * 4 + w;
      float bke = bk[h * D_ + e];
      Esh[d][e] = acc[u][w] + bqd * t1[e] + t2d * bke + (float)K_ * bqd * bke;
    }
  }
  __syncthreads();
  if (tid < 64) {
    float m = -1e30f;
    for (int e = 0; e < 64; ++e) m = fmaxf(m, Esh[tid][e]);
    float ssum = 0.f;
    for (int e = 0; e < 64; ++e) {
      float p = __expf(Esh[tid][e] - m);
      Esh[tid][e] = p;
      ssum += p;
    }
    float inv = 1.f / ssum;
    for (int e = 0; e < 64; ++e) Esh[tid][e] *= inv;
  }
  __syncthreads();
  const float g = gamma[h];
  const float inv1g = 1.f / (1.f + g);
  if (tid < 64) {
    float a2 = 0.f;
    for (int e = 0; e < 64; ++e) a2 += bv[h * D_ + e] * Esh[tid][e];
    bfin[hb * D_ + tid] = g * a2 * inv1g;
  }
  float* at = attn + (size_t)hb * 4096;
#pragma unroll
  for (int r = 0; r < 16; ++r) {
    int idx = tid + 256 * r;
    at[idx] = Esh[idx >> 6][idx & 63];
  }
}

// Wft[hb][q][c] = bf16( (g * sum_e Wv[c,e]*attn[q,e] + Wp[c,q]) / (1+g) )
__global__ __launch_bounds__(256) void k_wfin(
    const float* __restrict__ Wv, const float* __restrict__ Wp,
    const float* __restrict__ gamma, const float* __restrict__ attn,
    u16* __restrict__ Wft) {
  const int ct = blockIdx.x;  // 0..7
  const int hb = blockIdx.y;  // h*8+b
  const int h = hb >> 3;
  __shared__ float As[64][65];
  __shared__ float Vs[64][65];
  const int tid = threadIdx.x;
  const float* at = attn + (size_t)hb * 4096;
#pragma unroll
  for (int r = 0; r < 4; ++r) {
    int idx = tid + 256 * r;  // 0..1023
    int row = idx >> 4, e4 = (idx & 15) * 4;
    f32x4 av = *(const f32x4*)(at + row * 64 + e4);
    As[row][e4 + 0] = av[0]; As[row][e4 + 1] = av[1];
    As[row][e4 + 2] = av[2]; As[row][e4 + 3] = av[3];
    f32x4 vv = *(const f32x4*)(Wv + (size_t)(ct * 64 + row) * HD_ + h * D_ + e4);
    Vs[row][e4 + 0] = vv[0]; Vs[row][e4 + 1] = vv[1];
    Vs[row][e4 + 2] = vv[2]; Vs[row][e4 + 3] = vv[3];
  }
  __syncthreads();
  const float g = gamma[h];
  const float inv1g = 1.f / (1.f + g);
  const int q0 = (tid & 15) * 4, c0 = (tid >> 4) * 4;
  float s[4][4] = {};
  for (int e = 0; e < 64; e += 4) {
    float aq[4][4], vc[4][4];
#pragma unroll
    for (int u = 0; u < 4; ++u)
#pragma unroll
      for (int j = 0; j < 4; ++j) aq[u][j] = As[q0 + u][e + j];
#pragma unroll
    for (int w = 0; w < 4; ++w)
#pragma unroll
      for (int j = 0; j < 4; ++j) vc[w][j] = Vs[c0 + w][e + j];
#pragma unroll
    for (int u = 0; u < 4; ++u)
#pragma unroll
      for (int w = 0; w < 4; ++w)
#pragma unroll
        for (int j = 0; j < 4; ++j) s[u][w] += aq[u][j] * vc[w][j];
  }
  u16* Wf = Wft + (size_t)hb * D_ * IN_;
#pragma unroll
  for (int u = 0; u < 4; ++u)
#pragma unroll
    for (int w = 0; w < 4; ++w) {
      int q = q0 + u, c = ct * 64 + c0 + w;
      float val = (g * s[u][w] + Wp[(size_t)c * D_ + q]) * inv1g;
      Wf[(size_t)q * IN_ + c] = f2bf_rn(val);
    }
}

// out[b,h,kt*128..+128,:] = Y_b @ Wfin[hb] + bfin  (bf16 MFMA)
__global__ __launch_bounds__(256) void k_out_mfma(
    const u16* __restrict__ y_bf, const u16* __restrict__ Wft,
    const float* __restrict__ bfin, float* __restrict__ out) {
  const int kt = blockIdx.x;  // 0..31
  const int hb = blockIdx.y;  // h*8+b
  const int h = hb >> 3, b = hb & 7;
  __shared__ u16 Ys[128 * GP];
  __shared__ u16 Wsh[64 * GP];
  const int tid = threadIdx.x, wave = tid >> 6, lane = tid & 63;
  const int m16 = lane & 15, quad = lane >> 4;
  const size_t ybase = ((size_t)(b * K_ + kt * 128)) * IN_;
  const u16* Wf = Wft + (size_t)hb * D_ * IN_;
  f32x4 zf = {0.f, 0.f, 0.f, 0.f};
  f32x4 acc[2][4] = {{zf, zf, zf, zf}, {zf, zf, zf, zf}};
  for (int c0 = 0; c0 < IN_; c0 += 64) {
    __syncthreads();
#pragma unroll
    for (int r = 0; r < 4; ++r) {
      int idx = tid + 256 * r;  // 0..1023
      int row = idx >> 3, ck = (idx & 7) * 8;
      *(us8v*)&Ys[row * GP + ck] =
          *(const us8v*)(y_bf + ybase + (size_t)row * IN_ + c0 + ck);
    }
#pragma unroll
    for (int r = 0; r < 2; ++r) {
      int idx = tid + 256 * r;  // 0..511
      int row = idx >> 3, ck = (idx & 7) * 8;
      *(us8v*)&Wsh[row * GP + ck] =
          *(const us8v*)(Wf + (size_t)row * IN_ + c0 + ck);
    }
    __syncthreads();
#pragma unroll
    for (int kk = 0; kk < 64; kk += 32) {
      bf16x8 a0 = *(const bf16x8*)&Ys[(wave * 32 + m16) * GP + kk + quad * 8];
      bf16x8 a1 = *(const bf16x8*)&Ys[(wave * 32 + 16 + m16) * GP + kk + quad * 8];
#pragma unroll
      for (int n = 0; n < 4; ++n) {
        bf16x8 bb = *(const bf16x8*)&Wsh[(n * 16 + m16) * GP + kk + quad * 8];
        acc[0][n] = __builtin_amdgcn_mfma_f32_16x16x32_bf16(a0, bb, acc[0][n], 0, 0, 0);
        acc[1][n] = __builtin_amdgcn_mfma_f32_16x16x32_bf16(a1, bb, acc[1][n], 0, 0, 0);
      }
    }
  }
  float* ob = out + (((size_t)b * H_ + h) * K_) * D_;
#pragma unroll
  for (int ms = 0; ms < 2; ++ms)
#pragma unroll
    for (int n = 0; n < 4; ++n) {
      int col = n * 16 + m16;
      float bf = bfin[hb * D_ + col];
#pragma unroll
      for (int r = 0; r < 4; ++r) {
        int row = kt * 128 + wave * 32 + ms * 16 + quad * 4 + r;
        ob[(size_t)row * D_ + col] = acc[ms][n][r] + bf;
      }
    }
}

// =========================================================================
// Fallback f32 path (round-1 kernels), used if ws_size is too small
// =========================================================================
__global__ __launch_bounds__(256) void k_gram(const float* __restrict__ x,
                                              float* __restrict__ G,
                                              float* __restrict__ svec) {
  const int it = blockIdx.x, jt = blockIdx.y, b = blockIdx.z;
  if (jt < it) return;
  __shared__ float Xi[16][64];
  __shared__ float Xj[16][64];
  const float* Xb = x + (size_t)b * K_ * IN_;
  const int tx = threadIdx.x, ty = threadIdx.y;
  const int tid = ty * 16 + tx;
  const int i0 = it * 64, j0 = jt * 64;
  const bool diag = (it == jt);
  float acc[4][4] = {};
  float ssum = 0.f;
  for (int k0 = 0; k0 < K_; k0 += 16) {
#pragma unroll
    for (int r = 0; r < 4; ++r) {
      int idx = tid + 256 * r;
      int kk = idx >> 6, cc = idx & 63;
      const float* row = Xb + (size_t)(k0 + kk) * IN_;
      Xi[kk][cc] = row[i0 + cc];
      Xj[kk][cc] = row[j0 + cc];
    }
    __syncthreads();
#pragma unroll
    for (int kk = 0; kk < 16; ++kk) {
      float a[4], bb[4];
#pragma unroll
      for (int u = 0; u < 4; ++u) a[u] = Xi[kk][ty * 4 + u];
#pragma unroll
      for (int u = 0; u < 4; ++u) bb[u] = Xj[kk][tx * 4 + u];
#pragma unroll
      for (int u = 0; u < 4; ++u)
#pragma unroll
        for (int w = 0; w < 4; ++w) acc[u][w] += a[u] * bb[w];
    }
    if (diag && tid < 64) {
#pragma unroll
      for (int kk = 0; kk < 16; ++kk) ssum += Xi[kk][tid];
    }
    __syncthreads();
  }
  float* Gb = G + (size_t)b * IN_ * IN_;
#pragma unroll
  for (int u = 0; u < 4; ++u)
#pragma unroll
    for (int w = 0; w < 4; ++w) {
      int gi = i0 + ty * 4 + u, gj = j0 + tx * 4 + w;
      Gb[(size_t)gi * IN_ + gj] = acc[u][w];
      if (!diag) Gb[(size_t)gj * IN_ + gi] = acc[u][w];
    }
  if (diag && tid < 64) svec[b * IN_ + i0 + tid] = ssum;
}

__global__ __launch_bounds__(256) void k_attn_f32(
    const float* __restrict__ Wq, const float* __restrict__ Wk,
    const float* __restrict__ Wv, const float* __restrict__ Wp,
    const float* __restrict__ bq, const float* __restrict__ bk,
    const float* __restrict__ bv, const float* __restrict__ gamma,
    const float* __restrict__ Aall, const float* __restrict__ svec,
    float* __restrict__ Wfin, float* __restrict__ bfin) {
  const int h = blockIdx.x, b = blockIdx.y;
  const int hb = h * B_ + b;
  const int tx = threadIdx.x, ty = threadIdx.y;
  const int tid = ty * 16 + tx;
  __shared__ float Ast[64][17];
  __shared__ float Ws[16][64];
  __shared__ float Esh[64][65];
  __shared__ float t1[64], t2[64];
  const float* Ahb = Aall + (size_t)hb * D_ * IN_;
  if (tid < 64) {
    float a2 = 0.f;
    for (int c = 0; c < IN_; ++c)
      a2 += svec[b * IN_ + c] * Wk[(size_t)c * HD_ + h * D_ + tid];
    t1[tid] = a2;
  } else if (tid < 128) {
    int d = tid - 64;
    float a2 = 0.f;
    for (int c = 0; c < IN_; ++c)
      a2 += svec[b * IN_ + c] * Wq[(size_t)c * HD_ + h * D_ + d];
    t2[d] = a2;
  }
  float acc[4][4] = {};
  for (int c0 = 0; c0 < IN_; c0 += 16) {
#pragma unroll
    for (int r = 0; r < 4; ++r) {
      int idx = tid + 256 * r;
      int dd = idx >> 4, kk = idx & 15;
      Ast[dd][kk] = Ahb[(size_t)dd * IN_ + c0 + kk];
      int kk2 = idx >> 6, ee = idx & 63;
      Ws[kk2][ee] = Wk[(size_t)(c0 + kk2) * HD_ + h * D_ + ee];
    }
    __syncthreads();
#pragma unroll
    for (int kk = 0; kk < 16; ++kk) {
      float a[4], bb[4];
#pragma unroll
      for (int u = 0; u < 4; ++u) a[u] = Ast[ty * 4 + u][kk];
#pragma unroll
      for (int u = 0; u < 4; ++u) bb[u] = Ws[kk][tx * 4 + u];
#pragma unroll
      for (int u = 0; u < 4; ++u)
#pragma unroll
        for (int w = 0; w < 4; ++w) acc[u][w] += a[u] * bb[w];
    }
    __syncthreads();
  }
#pragma unroll
  for (int u = 0; u < 4; ++u) {
    int d = ty * 4 + u;
    float bqd = bq[h * D_ + d];
    float t2d = t2[d];
#pragma unroll
    for (int w = 0; w < 4; ++w) {
      int e = tx * 4 + w;
      float bke = bk[h * D_ + e];
      Esh[d][e] = acc[u][w] + bqd * t1[e] + t2d * bke + (float)K_ * bqd * bke;
    }
  }
  __syncthreads();
  if (tid < 64) {
    float m = -1e30f;
    for (int e = 0; e < 64; ++e) m = fmaxf(m, Esh[tid][e]);
    float ssum = 0.f;
    for (int e = 0; e < 64; ++e) {
      float p = __expf(Esh[tid][e] - m);
      Esh[tid][e] = p;
      ssum += p;
    }
    float inv = 1.f / ssum;
    for (int e = 0; e < 64; ++e) Esh[tid][e] *= inv;
  }
  __syncthreads();
  const float g = gamma[h];
  const float inv1g = 1.f / (1.f + g);
  if (tid < 64) {
    float a2 = 0.f;
    for (int e = 0; e < 64; ++e) a2 += bv[h * D_ + e] * Esh[tid][e];
    bfin[hb * D_ + tid] = g * a2 * inv1g;
  }
  float* Wf = Wfin + (size_t)hb * IN_ * D_;
  for (int it2 = 0; it2 < 128; ++it2) {
    int idx = tid + 256 * it2;
    int c = idx >> 6, q = idx & 63;
    const float* Wvr = Wv + (size_t)c * HD_ + h * D_;
    float a2 = 0.f;
#pragma unroll
    for (int e = 0; e < 64; ++e) a2 += Wvr[e] * Esh[q][e];
    Wf[idx] = (g * a2 + Wp[(size_t)c * D_ + q]) * inv1g;
  }
}

__global__ __launch_bounds__(256) void k_out_f32(const float* __restrict__ y,
                                                 const float* __restrict__ Wfin,
                                                 const float* __restrict__ bfin,
                                                 float* __restrict__ out) {
  const int kt = blockIdx.x;
  const int hb = blockIdx.y;
  const int h = hb >> 3, b = hb & 7;
  __shared__ float Ys[64][17];
  __shared__ float Ws[16][64];
  const int tx = threadIdx.x, ty = threadIdx.y;
  const int tid = ty * 16 + tx;
  const float* Yb = y + (size_t)b * K_ * IN_;
  const float* Wf = Wfin + (size_t)hb * IN_ * D_;
  const int k0 = kt * 64;
  float acc[4][4] = {};
  for (int c0 = 0; c0 < IN_; c0 += 16) {
#pragma unroll
    for (int r = 0; r < 4; ++r) {
      int idx = tid + 256 * r;
      int rr = idx >> 4, kk = idx & 15;
      Ys[rr][kk] = Yb[(size_t)(k0 + rr) * IN_ + c0 + kk];
      int kk2 = idx >> 6, qq = idx & 63;
      Ws[kk2][qq] = Wf[(size_t)(c0 + kk2) * D_ + qq];
    }
    __syncthreads();
#pragma unroll
    for (int kk = 0; kk < 16; ++kk) {
      float a[4], bb[4];
#pragma unroll
      for (int u = 0; u < 4; ++u) a[u] = Ys[ty * 4 + u][kk];
#pragma unroll
      for (int u = 0; u < 4; ++u) bb[u] = Ws[kk][tx * 4 + u];
#pragma unroll
      for (int u = 0; u < 4; ++u)
#pragma unroll
        for (int w = 0; w < 4; ++w) acc[u][w] += a[u] * bb[w];
    }
    __syncthreads();
  }
  float* ob = out + (((size_t)b * H_ + h) * K_ + k0) * D_;
#pragma unroll
  for (int u = 0; u < 4; ++u) {
    int k = ty * 4 + u;
#pragma unroll
    for (int w = 0; w < 4; ++w) {
      int q = tx * 4 + w;
      ob[(size_t)k * D_ + q] = acc[u][w] + bfin[hb * D_ + q];
    }
  }
}

// =========================================================================
extern "C" void kernel_launch(void* const* d_in, const int* in_sizes, int n_in,
                              void* d_out, int out_size, void* d_ws,
                              size_t ws_size, hipStream_t stream) {
  const float* x = (const float*)d_in[0];
  const float* y = (const float*)d_in[1];
  const float* Wq = (const float*)d_in[2];
  const float* bq = (const float*)d_in[3];
  const float* Wk = (const float*)d_in[4];
  const float* bk = (const float*)d_in[5];
  const float* Wv = (const float*)d_in[6];
  const float* bv = (const float*)d_in[7];
  const float* Wp = (const float*)d_in[8];
  const float* gm = (const float*)d_in[9];
  float* out = (float*)d_out;

  const size_t NEED = 122716160;
  if (ws_size >= NEED) {
    char* w = (char*)d_ws;
    u16* xt_hi = (u16*)(w);
    u16* xt_lo = (u16*)(w + 33554432);
    u16* y_bf = (u16*)(w + 67108864);
    float* G = (float*)(w + 100663296);
    float* Aall = (float*)(w + 109051904);
    u16* Wft = (u16*)(w + 117440512);
    float* attn = (float*)(w + 121634816);
    float* bfin = (float*)(w + 122683392);
    float* svec = (float*)(w + 122699776);

    hipMemsetAsync(svec, 0, B_ * IN_ * sizeof(float), stream);
    k_cvt_x<<<dim3(64, 8, 8), 256, 0, stream>>>(x, xt_hi, xt_lo, svec);
    k_cvt_y<<<8192, 256, 0, stream>>>(y, y_bf);
    k_gram_mfma<<<dim3(8, 8, 8), 256, 0, stream>>>(xt_hi, xt_lo, G);
    k_aall<<<dim3(8, 8, 8), dim3(16, 16), 0, stream>>>(Wq, G, Aall);
    k_attn2<<<dim3(8, 8), dim3(16, 16), 0, stream>>>(Wq, Wk, bq, bk, bv, gm,
                                                     Aall, svec, attn, bfin);
    k_wfin<<<dim3(8, 64), 256, 0, stream>>>(Wv, Wp, gm, attn, Wft);
    k_out_mfma<<<dim3(32, 64), 256, 0, stream>>>(y_bf, Wft, bfin, out);
  } else {
    float* ws = (float*)d_ws;
    float* G = ws;
    float* Aall = ws + 2097152;
    float* Wfin = ws + 4194304;
    float* bfin = ws + 6291456;
    float* svec = ws + 6295552;
    dim3 blk(16, 16);
    k_gram<<<dim3(8, 8, 8), blk, 0, stream>>>(x, G, svec);
    k_aall<<<dim3(8, 8, 8), blk, 0, stream>>>(Wq, G, Aall);
    k_attn_f32<<<dim3(8, 8), blk, 0, stream>>>(Wq, Wk, Wv, Wp, bq, bk, bv, gm,
                                               Aall, svec, Wfin, bfin);
    k_out_f32<<<dim3(64, 64), blk, 0, stream>>>(y, Wfin, bfin, out);
  }
}

// Round 3
// 357.961 us; speedup vs baseline: 2.6785x; 1.1962x over previous
//
#include <hip/hip_runtime.h>

#define B_ 8
#define K_ 4096
#define IN_ 512
#define H_ 8
#define D_ 64
#define HD_ 512  // H_*D_

typedef short bf16x8 __attribute__((ext_vector_type(8)));
typedef float f32x4 __attribute__((ext_vector_type(4)));
typedef unsigned short u16;
typedef unsigned short us8v __attribute__((ext_vector_type(8)));
typedef unsigned short us4v __attribute__((ext_vector_type(4)));

__device__ inline u16 f2bf_rn(float f) {
  unsigned u = __float_as_uint(f);
  u += 0x7fffu + ((u >> 16) & 1u);
  return (u16)(u >> 16);
}
__device__ inline float bf2f(u16 h) {
  return __uint_as_float(((unsigned)h) << 16);
}

// =========================================================================
// ws layout (bytes), fast path:
//   region0 [0, 33554432):
//     phase1: xt_hi [B][IN][K] bf16
//     phase2 (after k_gram): Ahi @0 (4MB), Alo @4MB, Wft @8MB (4MB)
//   xt_lo  @33554432  [B][IN][K] bf16 (32MB)
//   y_bf   @67108864  [B][K][IN] bf16 (32MB)
//   G      @100663296 [B][IN][IN] f32 (8MB)
//   Ghi    @109051904 (4MB)   Glo @113246208 (4MB)
//   Wqt_hi @117440512 (512KB) Wqt_lo @117964800
//   Wkt_hi @118489088         Wkt_lo @119013376
//   bfin   @119537664 (16KB)  svec @119554048 (16KB)
//   NEED = 119570432
// =========================================================================

// x (B,K,IN) f32 -> xt_hi/xt_lo (B,IN,K) bf16 split, + column sums (atomic)
__global__ __launch_bounds__(256) void k_cvt_x(const float* __restrict__ x,
                                               u16* __restrict__ xt_hi,
                                               u16* __restrict__ xt_lo,
                                               float* __restrict__ svec) {
  const int kt = blockIdx.x, ct = blockIdx.y, b = blockIdx.z;
  __shared__ float Xs[64][65];
  const int tid = threadIdx.x;
  const float* src = x + ((size_t)b * K_ + kt * 64) * IN_ + ct * 64;
#pragma unroll
  for (int r = 0; r < 4; ++r) {
    int idx = tid + 256 * r;  // 0..1023
    int k = idx >> 4, c4 = (idx & 15) * 4;
    f32x4 v = *(const f32x4*)(src + (size_t)k * IN_ + c4);
    Xs[k][c4 + 0] = v[0];
    Xs[k][c4 + 1] = v[1];
    Xs[k][c4 + 2] = v[2];
    Xs[k][c4 + 3] = v[3];
  }
  __syncthreads();
  if (tid < 64) {
    float s = 0.f;
#pragma unroll
    for (int k = 0; k < 64; ++k) s += Xs[k][tid];
    atomicAdd(&svec[b * IN_ + ct * 64 + tid], s);
  }
#pragma unroll
  for (int r = 0; r < 2; ++r) {
    int idx = tid + 256 * r;  // 0..511
    int c = idx >> 3, ck = (idx & 7) * 8;
    us8v hv, lv;
#pragma unroll
    for (int j = 0; j < 8; ++j) {
      float f = Xs[ck + j][c];
      u16 h = f2bf_rn(f);
      float lo = f - bf2f(h);
      hv[j] = h;
      lv[j] = f2bf_rn(lo);
    }
    size_t off = ((size_t)(b * IN_ + ct * 64 + c)) * K_ + kt * 64 + ck;
    *(us8v*)(xt_hi + off) = hv;
    *(us8v*)(xt_lo + off) = lv;
  }
}

// y (B,K,IN) f32 -> y_bf bf16 (same layout)
__global__ __launch_bounds__(256) void k_cvt_y(const float* __restrict__ y,
                                               u16* __restrict__ y_bf) {
  size_t i = ((size_t)blockIdx.x * 256 + threadIdx.x) * 8;
  f32x4 a = *(const f32x4*)(y + i);
  f32x4 b = *(const f32x4*)(y + i + 4);
  us8v o;
  o[0] = f2bf_rn(a[0]); o[1] = f2bf_rn(a[1]);
  o[2] = f2bf_rn(a[2]); o[3] = f2bf_rn(a[3]);
  o[4] = f2bf_rn(b[0]); o[5] = f2bf_rn(b[1]);
  o[6] = f2bf_rn(b[2]); o[7] = f2bf_rn(b[3]);
  *(us8v*)(y_bf + i) = o;
}

// Wq/Wk (512x512) -> transposed bf16 hi/lo: Wt[dcol][c] = W[c][dcol]
__global__ __launch_bounds__(256) void k_cvt_w(
    const float* __restrict__ Wq, const float* __restrict__ Wk,
    u16* __restrict__ Wqt_hi, u16* __restrict__ Wqt_lo,
    u16* __restrict__ Wkt_hi, u16* __restrict__ Wkt_lo) {
  const int ti = blockIdx.x, tj = blockIdx.y;
  const float* src = blockIdx.z ? Wk : Wq;
  u16* dhi = blockIdx.z ? Wkt_hi : Wqt_hi;
  u16* dlo = blockIdx.z ? Wkt_lo : Wqt_lo;
  __shared__ float T[64][65];
  const int tid = threadIdx.x;
#pragma unroll
  for (int r = 0; r < 4; ++r) {
    int idx = tid + 256 * r;
    int rr = idx >> 4, c4 = (idx & 15) * 4;
    f32x4 v = *(const f32x4*)(src + (size_t)(tj * 64 + rr) * 512 + ti * 64 + c4);
    T[rr][c4 + 0] = v[0]; T[rr][c4 + 1] = v[1];
    T[rr][c4 + 2] = v[2]; T[rr][c4 + 3] = v[3];
  }
  __syncthreads();
#pragma unroll
  for (int r = 0; r < 2; ++r) {
    int idx = tid + 256 * r;
    int d = idx >> 3, ck = (idx & 7) * 8;
    us8v hv, lv;
#pragma unroll
    for (int j = 0; j < 8; ++j) {
      float f = T[ck + j][d];
      u16 h = f2bf_rn(f);
      hv[j] = h;
      lv[j] = f2bf_rn(f - bf2f(h));
    }
    size_t off = (size_t)(ti * 64 + d) * 512 + tj * 64 + ck;
    *(us8v*)(dhi + off) = hv;
    *(us8v*)(dlo + off) = lv;
  }
}

#define GP 72  // padded LDS row (64 bf16 + 8) = 144 B

// G_b += X^T X (K-chunked), bf16x3 MFMA, upper-triangle blocks + full diag.
__global__ __launch_bounds__(256) void k_gram_mfma(
    const u16* __restrict__ xt_hi, const u16* __restrict__ xt_lo,
    float* __restrict__ G) {
  const int it = blockIdx.x, jt = blockIdx.y;
  const int b = blockIdx.z >> 2, kc = blockIdx.z & 3;
  if (jt < it) return;
  __shared__ u16 Pih[64 * GP], Pil[64 * GP], Pjh[64 * GP], Pjl[64 * GP];
  const int tid = threadIdx.x;
  const int wave = tid >> 6, lane = tid & 63;
  const int m16 = lane & 15, quad = lane >> 4;
  const size_t base_i = ((size_t)(b * IN_ + it * 64)) * K_;
  const size_t base_j = ((size_t)(b * IN_ + jt * 64)) * K_;
  f32x4 zf = {0.f, 0.f, 0.f, 0.f};
  f32x4 acc[4] = {zf, zf, zf, zf};
  const int kbeg = kc * 1024, kend = kbeg + 1024;
  for (int k0 = kbeg; k0 < kend; k0 += 64) {
    __syncthreads();
#pragma unroll
    for (int r = 0; r < 2; ++r) {
      int idx = tid + 256 * r;  // 0..511
      int row = idx >> 3, ck = (idx & 7) * 8;
      size_t gi = base_i + (size_t)row * K_ + k0 + ck;
      size_t gj = base_j + (size_t)row * K_ + k0 + ck;
      int lo = row * GP + ck;
      *(us8v*)&Pih[lo] = *(const us8v*)(xt_hi + gi);
      *(us8v*)&Pil[lo] = *(const us8v*)(xt_lo + gi);
      *(us8v*)&Pjh[lo] = *(const us8v*)(xt_hi + gj);
      *(us8v*)&Pjl[lo] = *(const us8v*)(xt_lo + gj);
    }
    __syncthreads();
#pragma unroll
    for (int kk = 0; kk < 64; kk += 32) {
      int arow = (wave * 16 + m16) * GP + kk + quad * 8;
      bf16x8 ah = *(const bf16x8*)&Pih[arow];
      bf16x8 al = *(const bf16x8*)&Pil[arow];
#pragma unroll
      for (int n = 0; n < 4; ++n) {
        int brow = (n * 16 + m16) * GP + kk + quad * 8;
        bf16x8 bh = *(const bf16x8*)&Pjh[brow];
        bf16x8 bl = *(const bf16x8*)&Pjl[brow];
        acc[n] = __builtin_amdgcn_mfma_f32_16x16x32_bf16(ah, bh, acc[n], 0, 0, 0);
        acc[n] = __builtin_amdgcn_mfma_f32_16x16x32_bf16(ah, bl, acc[n], 0, 0, 0);
        acc[n] = __builtin_amdgcn_mfma_f32_16x16x32_bf16(al, bh, acc[n], 0, 0, 0);
      }
    }
  }
  float* Gb = G + (size_t)b * IN_ * IN_;
#pragma unroll
  for (int n = 0; n < 4; ++n) {
#pragma unroll
    for (int r = 0; r < 4; ++r) {
      int gi = it * 64 + wave * 16 + quad * 4 + r;
      int gj = jt * 64 + n * 16 + m16;
      atomicAdd(&Gb[(size_t)gi * IN_ + gj], acc[n][r]);
    }
  }
}

// G f32 (upper blocks + diag) -> Ghi/Glo bf16, mirroring lower blocks
__global__ __launch_bounds__(256) void k_cvt_g(const float* __restrict__ G,
                                               u16* __restrict__ Ghi,
                                               u16* __restrict__ Glo) {
  const int ti = blockIdx.x, tj = blockIdx.y, b = blockIdx.z;
  if (tj < ti) return;
  const float* Gb = G + (size_t)b * IN_ * IN_;
  u16* ghb = Ghi + (size_t)b * IN_ * IN_;
  u16* glb = Glo + (size_t)b * IN_ * IN_;
  __shared__ float T[64][65];
  const int tid = threadIdx.x;
#pragma unroll
  for (int r = 0; r < 4; ++r) {
    int idx = tid + 256 * r;
    int rr = idx >> 4, c4 = (idx & 15) * 4;
    f32x4 v = *(const f32x4*)(Gb + (size_t)(ti * 64 + rr) * IN_ + tj * 64 + c4);
    T[rr][c4 + 0] = v[0]; T[rr][c4 + 1] = v[1];
    T[rr][c4 + 2] = v[2]; T[rr][c4 + 3] = v[3];
  }
  __syncthreads();
#pragma unroll
  for (int r = 0; r < 2; ++r) {
    int idx = tid + 256 * r;
    int rr = idx >> 3, ck = (idx & 7) * 8;
    us8v hv, lv;
#pragma unroll
    for (int j = 0; j < 8; ++j) {
      float f = T[rr][ck + j];
      u16 h = f2bf_rn(f);
      hv[j] = h;
      lv[j] = f2bf_rn(f - bf2f(h));
    }
    size_t off = (size_t)(ti * 64 + rr) * IN_ + tj * 64 + ck;
    *(us8v*)(ghb + off) = hv;
    *(us8v*)(glb + off) = lv;
  }
  if (ti != tj) {
#pragma unroll
    for (int r = 0; r < 2; ++r) {
      int idx = tid + 256 * r;
      int rr = idx >> 3, ck = (idx & 7) * 8;
      us8v hv, lv;
#pragma unroll
      for (int j = 0; j < 8; ++j) {
        float f = T[ck + j][rr];  // mirrored element
        u16 h = f2bf_rn(f);
        hv[j] = h;
        lv[j] = f2bf_rn(f - bf2f(h));
      }
      size_t off = (size_t)(tj * 64 + rr) * IN_ + ti * 64 + ck;
      *(us8v*)(ghb + off) = hv;
      *(us8v*)(glb + off) = lv;
    }
  }
}

// A[hb] = Wqt_h (64x512) @ G_b (512x512, symmetric), 3-product MFMA.
// Output written as bf16 hi/lo [hb][d][c'].
__global__ __launch_bounds__(256) void k_aall_mfma(
    const u16* __restrict__ Wqt_hi, const u16* __restrict__ Wqt_lo,
    const u16* __restrict__ Ghi, const u16* __restrict__ Glo,
    u16* __restrict__ Ahi, u16* __restrict__ Alo) {
  const int ct = blockIdx.x;  // c' tile 0..7
  const int hb = blockIdx.y;  // h*8+b
  const int h = hb >> 3, b = hb & 7;
  __shared__ u16 S[4 * 64 * GP];
  u16* Ah = S;
  u16* Al = S + 64 * GP;
  u16* Bh = S + 2 * 64 * GP;
  u16* Bl = S + 3 * 64 * GP;
  const int tid = threadIdx.x;
  const int wave = tid >> 6, lane = tid & 63;
  const int m16 = lane & 15, quad = lane >> 4;
  const u16* Abase_h = Wqt_hi + (size_t)(h * 64) * IN_;
  const u16* Abase_l = Wqt_lo + (size_t)(h * 64) * IN_;
  const u16* Bbase_h = Ghi + (size_t)b * IN_ * IN_ + (size_t)(ct * 64) * IN_;
  const u16* Bbase_l = Glo + (size_t)b * IN_ * IN_ + (size_t)(ct * 64) * IN_;
  f32x4 zf = {0.f, 0.f, 0.f, 0.f};
  f32x4 acc[4] = {zf, zf, zf, zf};
  for (int k0 = 0; k0 < IN_; k0 += 64) {
    __syncthreads();
#pragma unroll
    for (int r = 0; r < 2; ++r) {
      int idx = tid + 256 * r;
      int row = idx >> 3, ck = (idx & 7) * 8;
      int lo = row * GP + ck;
      *(us8v*)&Ah[lo] = *(const us8v*)(Abase_h + (size_t)row * IN_ + k0 + ck);
      *(us8v*)&Al[lo] = *(const us8v*)(Abase_l + (size_t)row * IN_ + k0 + ck);
      *(us8v*)&Bh[lo] = *(const us8v*)(Bbase_h + (size_t)row * IN_ + k0 + ck);
      *(us8v*)&Bl[lo] = *(const us8v*)(Bbase_l + (size_t)row * IN_ + k0 + ck);
    }
    __syncthreads();
#pragma unroll
    for (int kk = 0; kk < 64; kk += 32) {
      int arow = (wave * 16 + m16) * GP + kk + quad * 8;
      bf16x8 ah = *(const bf16x8*)&Ah[arow];
      bf16x8 al = *(const bf16x8*)&Al[arow];
#pragma unroll
      for (int n = 0; n < 4; ++n) {
        int brow = (n * 16 + m16) * GP + kk + quad * 8;
        bf16x8 bh = *(const bf16x8*)&Bh[brow];
        bf16x8 bl = *(const bf16x8*)&Bl[brow];
        acc[n] = __builtin_amdgcn_mfma_f32_16x16x32_bf16(ah, bh, acc[n], 0, 0, 0);
        acc[n] = __builtin_amdgcn_mfma_f32_16x16x32_bf16(ah, bl, acc[n], 0, 0, 0);
        acc[n] = __builtin_amdgcn_mfma_f32_16x16x32_bf16(al, bh, acc[n], 0, 0, 0);
      }
    }
  }
  // bounce through LDS (reuse S as f32 64x68) for coalesced hi/lo stores
  __syncthreads();
  float* Sf = (float*)S;
#pragma unroll
  for (int n = 0; n < 4; ++n)
#pragma unroll
    for (int r = 0; r < 4; ++r) {
      int d = wave * 16 + quad * 4 + r;
      int cc = n * 16 + m16;
      Sf[d * 68 + cc] = acc[n][r];
    }
  __syncthreads();
#pragma unroll
  for (int r = 0; r < 2; ++r) {
    int idx = tid + 256 * r;
    int d = idx >> 3, ck = (idx & 7) * 8;
    us8v hv, lv;
#pragma unroll
    for (int j = 0; j < 8; ++j) {
      float f = Sf[d * 68 + ck + j];
      u16 h2 = f2bf_rn(f);
      hv[j] = h2;
      lv[j] = f2bf_rn(f - bf2f(h2));
    }
    size_t off = ((size_t)hb * 64 + d) * IN_ + ct * 64 + ck;
    *(us8v*)(Ahi + off) = hv;
    *(us8v*)(Alo + off) = lv;
  }
}

// per (h,b): E = A @ Wk (MFMA 3-product) + bias, softmax, bfin,
// then Wft[q][c] = bf16((g * sum_e Wv[c,e]*attn[q,e] + Wp[c,q])/(1+g)) via MFMA
__global__ __launch_bounds__(256) void k_attn3(
    const u16* __restrict__ Ahi, const u16* __restrict__ Alo,
    const u16* __restrict__ Wqt_hi, const u16* __restrict__ Wqt_lo,
    const u16* __restrict__ Wkt_hi, const u16* __restrict__ Wkt_lo,
    const float* __restrict__ Wv, const float* __restrict__ Wp,
    const float* __restrict__ bq, const float* __restrict__ bk,
    const float* __restrict__ bv, const float* __restrict__ gamma,
    const float* __restrict__ svec, u16* __restrict__ Wft,
    float* __restrict__ bfin) {
  const int h = blockIdx.x, b = blockIdx.y;
  const int hb = h * B_ + b;
  const int tid = threadIdx.x;
  const int wave = tid >> 6, lane = tid & 63;
  const int m16 = lane & 15, quad = lane >> 4;
  __shared__ u16 S[4 * 64 * GP];
  __shared__ float Esh[64][65];
  __shared__ float t1[64], t2[64];
  u16* Ah = S;
  u16* Al = S + 64 * GP;
  u16* Bh = S + 2 * 64 * GP;
  u16* Bl = S + 3 * 64 * GP;

  // bias helper vectors (exact zeros when biases are zero)
  if (tid < 64) {
    float s = 0.f;
    const u16* wh = Wkt_hi + (size_t)(h * 64 + tid) * IN_;
    const u16* wl = Wkt_lo + (size_t)(h * 64 + tid) * IN_;
    for (int c = 0; c < IN_; ++c)
      s += svec[b * IN_ + c] * (bf2f(wh[c]) + bf2f(wl[c]));
    t1[tid] = s;
  } else if (tid < 128) {
    int d = tid - 64;
    float s = 0.f;
    const u16* wh = Wqt_hi + (size_t)(h * 64 + d) * IN_;
    const u16* wl = Wqt_lo + (size_t)(h * 64 + d) * IN_;
    for (int c = 0; c < IN_; ++c)
      s += svec[b * IN_ + c] * (bf2f(wh[c]) + bf2f(wl[c]));
    t2[d] = s;
  }

  const u16* Abase_h = Ahi + (size_t)hb * 64 * IN_;
  const u16* Abase_l = Alo + (size_t)hb * 64 * IN_;
  const u16* Bbase_h = Wkt_hi + (size_t)(h * 64) * IN_;
  const u16* Bbase_l = Wkt_lo + (size_t)(h * 64) * IN_;
  f32x4 zf = {0.f, 0.f, 0.f, 0.f};
  f32x4 acc[4] = {zf, zf, zf, zf};
  for (int k0 = 0; k0 < IN_; k0 += 64) {
    __syncthreads();
#pragma unroll
    for (int r = 0; r < 2; ++r) {
      int idx = tid + 256 * r;
      int row = idx >> 3, ck = (idx & 7) * 8;
      int lo = row * GP + ck;
      *(us8v*)&Ah[lo] = *(const us8v*)(Abase_h + (size_t)row * IN_ + k0 + ck);
      *(us8v*)&Al[lo] = *(const us8v*)(Abase_l + (size_t)row * IN_ + k0 + ck);
      *(us8v*)&Bh[lo] = *(const us8v*)(Bbase_h + (size_t)row * IN_ + k0 + ck);
      *(us8v*)&Bl[lo] = *(const us8v*)(Bbase_l + (size_t)row * IN_ + k0 + ck);
    }
    __syncthreads();
#pragma unroll
    for (int kk = 0; kk < 64; kk += 32) {
      int arow = (wave * 16 + m16) * GP + kk + quad * 8;
      bf16x8 ah = *(const bf16x8*)&Ah[arow];
      bf16x8 al = *(const bf16x8*)&Al[arow];
#pragma unroll
      for (int n = 0; n < 4; ++n) {
        int brow = (n * 16 + m16) * GP + kk + quad * 8;
        bf16x8 bh = *(const bf16x8*)&Bh[brow];
        bf16x8 bl = *(const bf16x8*)&Bl[brow];
        acc[n] = __builtin_amdgcn_mfma_f32_16x16x32_bf16(ah, bh, acc[n], 0, 0, 0);
        acc[n] = __builtin_amdgcn_mfma_f32_16x16x32_bf16(ah, bl, acc[n], 0, 0, 0);
        acc[n] = __builtin_amdgcn_mfma_f32_16x16x32_bf16(al, bh, acc[n], 0, 0, 0);
      }
    }
  }
  __syncthreads();
  // E into LDS with bias terms
#pragma unroll
  for (int n = 0; n < 4; ++n)
#pragma unroll
    for (int r = 0; r < 4; ++r) {
      int d = wave * 16 + quad * 4 + r;
      int e = n * 16 + m16;
      float bqd = bq[h * D_ + d], bke = bk[h * D_ + e];
      Esh[d][e] = acc[n][r] + bqd * t1[e] + t2[d] * bke + (float)K_ * bqd * bke;
    }
  __syncthreads();
  const float g = gamma[h];
  const float inv1g = 1.f / (1.f + g);
  if (tid < 64) {
    float m = -1e30f;
    for (int e = 0; e < 64; ++e) m = fmaxf(m, Esh[tid][e]);
    float ssum = 0.f;
    for (int e = 0; e < 64; ++e) {
      float p = __expf(Esh[tid][e] - m);
      Esh[tid][e] = p;
      ssum += p;
    }
    float inv = 1.f / ssum;
    float bsum = 0.f;
    for (int e = 0; e < 64; ++e) {
      Esh[tid][e] *= inv;
      bsum += bv[h * D_ + e] * Esh[tid][e];
    }
    bfin[hb * D_ + tid] = g * bsum * inv1g;
  }
  __syncthreads();

  // Phase W: D[m=c][n=q] = sum_e Wv[c][e] * attn[q][e]
  bf16x8 bfr[4][2];
#pragma unroll
  for (int n = 0; n < 4; ++n)
#pragma unroll
    for (int kk = 0; kk < 2; ++kk)
#pragma unroll
      for (int j = 0; j < 8; ++j)
        bfr[n][kk][j] = f2bf_rn(Esh[n * 16 + m16][kk * 32 + quad * 8 + j]);

  u16* Wf = Wft + (size_t)hb * D_ * IN_;
#pragma unroll
  for (int mt = 0; mt < 8; ++mt) {
    f32x4 a4[4] = {zf, zf, zf, zf};
#pragma unroll
    for (int kk = 0; kk < 2; ++kk) {
      int c = wave * 128 + mt * 16 + m16;
      const float* wv = Wv + (size_t)c * HD_ + h * D_ + kk * 32 + quad * 8;
      f32x4 v0 = *(const f32x4*)wv;
      f32x4 v1 = *(const f32x4*)(wv + 4);
      bf16x8 af;
      af[0] = f2bf_rn(v0[0]); af[1] = f2bf_rn(v0[1]);
      af[2] = f2bf_rn(v0[2]); af[3] = f2bf_rn(v0[3]);
      af[4] = f2bf_rn(v1[0]); af[5] = f2bf_rn(v1[1]);
      af[6] = f2bf_rn(v1[2]); af[7] = f2bf_rn(v1[3]);
#pragma unroll
      for (int n = 0; n < 4; ++n)
        a4[n] = __builtin_amdgcn_mfma_f32_16x16x32_bf16(af, bfr[n][kk], a4[n], 0, 0, 0);
    }
    int cb = wave * 128 + mt * 16 + quad * 4;
#pragma unroll
    for (int n = 0; n < 4; ++n) {
      int q = n * 16 + m16;
      us4v st;
#pragma unroll
      for (int r = 0; r < 4; ++r) {
        float val = (g * a4[n][r] + Wp[(size_t)(cb + r) * D_ + q]) * inv1g;
        st[r] = f2bf_rn(val);
      }
      *(us4v*)(Wf + (size_t)q * IN_ + cb) = st;
    }
  }
}

// out[b,h,kt*128..+128,:] = Y_b @ Wfin[hb] + bfin  (bf16 MFMA)
__global__ __launch_bounds__(256) void k_out_mfma(
    const u16* __restrict__ y_bf, const u16* __restrict__ Wft,
    const float* __restrict__ bfin, float* __restrict__ out) {
  const int kt = blockIdx.x;  // 0..31
  const int hb = blockIdx.y;  // h*8+b
  const int h = hb >> 3, b = hb & 7;
  __shared__ u16 Ys[128 * GP];
  __shared__ u16 Wsh[64 * GP];
  const int tid = threadIdx.x, wave = tid >> 6, lane = tid & 63;
  const int m16 = lane & 15, quad = lane >> 4;
  const size_t ybase = ((size_t)(b * K_ + kt * 128)) * IN_;
  const u16* Wf = Wft + (size_t)hb * D_ * IN_;
  f32x4 zf = {0.f, 0.f, 0.f, 0.f};
  f32x4 acc[2][4] = {{zf, zf, zf, zf}, {zf, zf, zf, zf}};
  for (int c0 = 0; c0 < IN_; c0 += 64) {
    __syncthreads();
#pragma unroll
    for (int r = 0; r < 4; ++r) {
      int idx = tid + 256 * r;  // 0..1023
      int row = idx >> 3, ck = (idx & 7) * 8;
      *(us8v*)&Ys[row * GP + ck] =
          *(const us8v*)(y_bf + ybase + (size_t)row * IN_ + c0 + ck);
    }
#pragma unroll
    for (int r = 0; r < 2; ++r) {
      int idx = tid + 256 * r;  // 0..511
      int row = idx >> 3, ck = (idx & 7) * 8;
      *(us8v*)&Wsh[row * GP + ck] =
          *(const us8v*)(Wf + (size_t)row * IN_ + c0 + ck);
    }
    __syncthreads();
#pragma unroll
    for (int kk = 0; kk < 64; kk += 32) {
      bf16x8 a0 = *(const bf16x8*)&Ys[(wave * 32 + m16) * GP + kk + quad * 8];
      bf16x8 a1 = *(const bf16x8*)&Ys[(wave * 32 + 16 + m16) * GP + kk + quad * 8];
#pragma unroll
      for (int n = 0; n < 4; ++n) {
        bf16x8 bb = *(const bf16x8*)&Wsh[(n * 16 + m16) * GP + kk + quad * 8];
        acc[0][n] = __builtin_amdgcn_mfma_f32_16x16x32_bf16(a0, bb, acc[0][n], 0, 0, 0);
        acc[1][n] = __builtin_amdgcn_mfma_f32_16x16x32_bf16(a1, bb, acc[1][n], 0, 0, 0);
      }
    }
  }
  float* ob = out + (((size_t)b * H_ + h) * K_) * D_;
#pragma unroll
  for (int ms = 0; ms < 2; ++ms)
#pragma unroll
    for (int n = 0; n < 4; ++n) {
      int col = n * 16 + m16;
      float bf = bfin[hb * D_ + col];
#pragma unroll
      for (int r = 0; r < 4; ++r) {
        int row = kt * 128 + wave * 32 + ms * 16 + quad * 4 + r;
        ob[(size_t)row * D_ + col] = acc[ms][n][r] + bf;
      }
    }
}

// =========================================================================
// Fallback f32 path (round-1 kernels), used if ws_size is too small
// =========================================================================
__global__ __launch_bounds__(256) void k_gram(const float* __restrict__ x,
                                              float* __restrict__ G,
                                              float* __restrict__ svec) {
  const int it = blockIdx.x, jt = blockIdx.y, b = blockIdx.z;
  if (jt < it) return;
  __shared__ float Xi[16][64];
  __shared__ float Xj[16][64];
  const float* Xb = x + (size_t)b * K_ * IN_;
  const int tx = threadIdx.x, ty = threadIdx.y;
  const int tid = ty * 16 + tx;
  const int i0 = it * 64, j0 = jt * 64;
  const bool diag = (it == jt);
  float acc[4][4] = {};
  float ssum = 0.f;
  for (int k0 = 0; k0 < K_; k0 += 16) {
#pragma unroll
    for (int r = 0; r < 4; ++r) {
      int idx = tid + 256 * r;
      int kk = idx >> 6, cc = idx & 63;
      const float* row = Xb + (size_t)(k0 + kk) * IN_;
      Xi[kk][cc] = row[i0 + cc];
      Xj[kk][cc] = row[j0 + cc];
    }
    __syncthreads();
#pragma unroll
    for (int kk = 0; kk < 16; ++kk) {
      float a[4], bb[4];
#pragma unroll
      for (int u = 0; u < 4; ++u) a[u] = Xi[kk][ty * 4 + u];
#pragma unroll
      for (int u = 0; u < 4; ++u) bb[u] = Xj[kk][tx * 4 + u];
#pragma unroll
      for (int u = 0; u < 4; ++u)
#pragma unroll
        for (int w = 0; w < 4; ++w) acc[u][w] += a[u] * bb[w];
    }
    if (diag && tid < 64) {
#pragma unroll
      for (int kk = 0; kk < 16; ++kk) ssum += Xi[kk][tid];
    }
    __syncthreads();
  }
  float* Gb = G + (size_t)b * IN_ * IN_;
#pragma unroll
  for (int u = 0; u < 4; ++u)
#pragma unroll
    for (int w = 0; w < 4; ++w) {
      int gi = i0 + ty * 4 + u, gj = j0 + tx * 4 + w;
      Gb[(size_t)gi * IN_ + gj] = acc[u][w];
      if (!diag) Gb[(size_t)gj * IN_ + gi] = acc[u][w];
    }
  if (diag && tid < 64) svec[b * IN_ + i0 + tid] = ssum;
}

__global__ __launch_bounds__(256) void k_aall(const float* __restrict__ Wq,
                                              const float* __restrict__ G,
                                              float* __restrict__ Aall) {
  const int jt = blockIdx.x;
  const int h = blockIdx.y, b = blockIdx.z;
  __shared__ float Ws[16][64];
  __shared__ float Gs[16][64];
  const float* Gb = G + (size_t)b * IN_ * IN_;
  const int tx = threadIdx.x, ty = threadIdx.y;
  const int tid = ty * 16 + tx;
  float acc[4][4] = {};
  for (int c0 = 0; c0 < IN_; c0 += 16) {
#pragma unroll
    for (int r = 0; r < 4; ++r) {
      int idx = tid + 256 * r;
      int kk = idx >> 6, cc = idx & 63;
      Ws[kk][cc] = Wq[(size_t)(c0 + kk) * HD_ + h * D_ + cc];
      Gs[kk][cc] = Gb[(size_t)(c0 + kk) * IN_ + jt * 64 + cc];
    }
    __syncthreads();
#pragma unroll
    for (int kk = 0; kk < 16; ++kk) {
      float a[4], bb[4];
#pragma unroll
      for (int u = 0; u < 4; ++u) a[u] = Ws[kk][ty * 4 + u];
#pragma unroll
      for (int u = 0; u < 4; ++u) bb[u] = Gs[kk][tx * 4 + u];
#pragma unroll
      for (int u = 0; u < 4; ++u)
#pragma unroll
        for (int w = 0; w < 4; ++w) acc[u][w] += a[u] * bb[w];
    }
    __syncthreads();
  }
  const int hb = h * B_ + b;
  float* Ahb = Aall + (size_t)hb * D_ * IN_;
#pragma unroll
  for (int u = 0; u < 4; ++u)
#pragma unroll
    for (int w = 0; w < 4; ++w)
      Ahb[(size_t)(ty * 4 + u) * IN_ + jt * 64 + tx * 4 + w] = acc[u][w];
}

__global__ __launch_bounds__(256) void k_attn_f32(
    const float* __restrict__ Wq, const float* __restrict__ Wk,
    const float* __restrict__ Wv, const float* __restrict__ Wp,
    const float* __restrict__ bq, const float* __restrict__ bk,
    const float* __restrict__ bv, const float* __restrict__ gamma,
    const float* __restrict__ Aall, const float* __restrict__ svec,
    float* __restrict__ Wfin, float* __restrict__ bfin) {
  const int h = blockIdx.x, b = blockIdx.y;
  const int hb = h * B_ + b;
  const int tx = threadIdx.x, ty = threadIdx.y;
  const int tid = ty * 16 + tx;
  __shared__ float Ast[64][17];
  __shared__ float Ws[16][64];
  __shared__ float Esh[64][65];
  __shared__ float t1[64], t2[64];
  const float* Ahb = Aall + (size_t)hb * D_ * IN_;
  if (tid < 64) {
    float a2 = 0.f;
    for (int c = 0; c < IN_; ++c)
      a2 += svec[b * IN_ + c] * Wk[(size_t)c * HD_ + h * D_ + tid];
    t1[tid] = a2;
  } else if (tid < 128) {
    int d = tid - 64;
    float a2 = 0.f;
    for (int c = 0; c < IN_; ++c)
      a2 += svec[b * IN_ + c] * Wq[(size_t)c * HD_ + h * D_ + d];
    t2[d] = a2;
  }
  float acc[4][4] = {};
  for (int c0 = 0; c0 < IN_; c0 += 16) {
#pragma unroll
    for (int r = 0; r < 4; ++r) {
      int idx = tid + 256 * r;
      int dd = idx >> 4, kk = idx & 15;
      Ast[dd][kk] = Ahb[(size_t)dd * IN_ + c0 + kk];
      int kk2 = idx >> 6, ee = idx & 63;
      Ws[kk2][ee] = Wk[(size_t)(c0 + kk2) * HD_ + h * D_ + ee];
    }
    __syncthreads();
#pragma unroll
    for (int kk = 0; kk < 16; ++kk) {
      float a[4], bb[4];
#pragma unroll
      for (int u = 0; u < 4; ++u) a[u] = Ast[ty * 4 + u][kk];
#pragma unroll
      for (int u = 0; u < 4; ++u) bb[u] = Ws[kk][tx * 4 + u];
#pragma unroll
      for (int u = 0; u < 4; ++u)
#pragma unroll
        for (int w = 0; w < 4; ++w) acc[u][w] += a[u] * bb[w];
    }
    __syncthreads();
  }
#pragma unroll
  for (int u = 0; u < 4; ++u) {
    int d = ty * 4 + u;
    float bqd = bq[h * D_ + d];
    float t2d = t2[d];
#pragma unroll
    for (int w = 0; w < 4; ++w) {
      int e = tx * 4 + w;
      float bke = bk[h * D_ + e];
      Esh[d][e] = acc[u][w] + bqd * t1[e] + t2d * bke + (float)K_ * bqd * bke;
    }
  }
  __syncthreads();
  if (tid < 64) {
    float m = -1e30f;
    for (int e = 0; e < 64; ++e) m = fmaxf(m, Esh[tid][e]);
    float ssum = 0.f;
    for (int e = 0; e < 64; ++e) {
      float p = __expf(Esh[tid][e] - m);
      Esh[tid][e] = p;
      ssum += p;
    }
    float inv = 1.f / ssum;
    for (int e = 0; e < 64; ++e) Esh[tid][e] *= inv;
  }
  __syncthreads();
  const float g = gamma[h];
  const float inv1g = 1.f / (1.f + g);
  if (tid < 64) {
    float a2 = 0.f;
    for (int e = 0; e < 64; ++e) a2 += bv[h * D_ + e] * Esh[tid][e];
    bfin[hb * D_ + tid] = g * a2 * inv1g;
  }
  float* Wf = Wfin + (size_t)hb * IN_ * D_;
  for (int it2 = 0; it2 < 128; ++it2) {
    int idx = tid + 256 * it2;
    int c = idx >> 6, q = idx & 63;
    const float* Wvr = Wv + (size_t)c * HD_ + h * D_;
    float a2 = 0.f;
#pragma unroll
    for (int e = 0; e < 64; ++e) a2 += Wvr[e] * Esh[q][e];
    Wf[idx] = (g * a2 + Wp[(size_t)c * D_ + q]) * inv1g;
  }
}

__global__ __launch_bounds__(256) void k_out_f32(const float* __restrict__ y,
                                                 const float* __restrict__ Wfin,
                                                 const float* __restrict__ bfin,
                                                 float* __restrict__ out) {
  const int kt = blockIdx.x;
  const int hb = blockIdx.y;
  const int h = hb >> 3, b = hb & 7;
  __shared__ float Ys[64][17];
  __shared__ float Ws[16][64];
  const int tx = threadIdx.x, ty = threadIdx.y;
  const int tid = ty * 16 + tx;
  const float* Yb = y + (size_t)b * K_ * IN_;
  const float* Wf = Wfin + (size_t)hb * IN_ * D_;
  const int k0 = kt * 64;
  float acc[4][4] = {};
  for (int c0 = 0; c0 < IN_; c0 += 16) {
#pragma unroll
    for (int r = 0; r < 4; ++r) {
      int idx = tid + 256 * r;
      int rr = idx >> 4, kk = idx & 15;
      Ys[rr][kk] = Yb[(size_t)(k0 + rr) * IN_ + c0 + kk];
      int kk2 = idx >> 6, qq = idx & 63;
      Ws[kk2][qq] = Wf[(size_t)(c0 + kk2) * D_ + qq];
    }
    __syncthreads();
#pragma unroll
    for (int kk = 0; kk < 16; ++kk) {
      float a[4], bb[4];
#pragma unroll
      for (int u = 0; u < 4; ++u) a[u] = Ys[ty * 4 + u][kk];
#pragma unroll
      for (int u = 0; u < 4; ++u) bb[u] = Ws[kk][tx * 4 + u];
#pragma unroll
      for (int u = 0; u < 4; ++u)
#pragma unroll
        for (int w = 0; w < 4; ++w) acc[u][w] += a[u] * bb[w];
    }
    __syncthreads();
  }
  float* ob = out + (((size_t)b * H_ + h) * K_ + k0) * D_;
#pragma unroll
  for (int u = 0; u < 4; ++u) {
    int k = ty * 4 + u;
#pragma unroll
    for (int w = 0; w < 4; ++w) {
      int q = tx * 4 + w;
      ob[(size_t)k * D_ + q] = acc[u][w] + bfin[hb * D_ + q];
    }
  }
}

// =========================================================================
extern "C" void kernel_launch(void* const* d_in, const int* in_sizes, int n_in,
                              void* d_out, int out_size, void* d_ws,
                              size_t ws_size, hipStream_t stream) {
  const float* x = (const float*)d_in[0];
  const float* y = (const float*)d_in[1];
  const float* Wq = (const float*)d_in[2];
  const float* bq = (const float*)d_in[3];
  const float* Wk = (const float*)d_in[4];
  const float* bk = (const float*)d_in[5];
  const float* Wv = (const float*)d_in[6];
  const float* bv = (const float*)d_in[7];
  const float* Wp = (const float*)d_in[8];
  const float* gm = (const float*)d_in[9];
  float* out = (float*)d_out;

  const size_t NEED = 119570432;
  if (ws_size >= NEED) {
    char* w = (char*)d_ws;
    // region0: xt_hi in phase 1; Ahi/Alo/Wft in phase 2 (xt_hi dead)
    u16* xt_hi = (u16*)(w);
    u16* Ahi = (u16*)(w);
    u16* Alo = (u16*)(w + 4194304);
    u16* Wft = (u16*)(w + 8388608);
    u16* xt_lo = (u16*)(w + 33554432);
    u16* y_bf = (u16*)(w + 67108864);
    float* G = (float*)(w + 100663296);
    u16* Ghi = (u16*)(w + 109051904);
    u16* Glo = (u16*)(w + 113246208);
    u16* Wqt_hi = (u16*)(w + 117440512);
    u16* Wqt_lo = (u16*)(w + 117964800);
    u16* Wkt_hi = (u16*)(w + 118489088);
    u16* Wkt_lo = (u16*)(w + 119013376);
    float* bfin = (float*)(w + 119537664);
    float* svec = (float*)(w + 119554048);

    hipMemsetAsync(G, 0, 8388608, stream);
    hipMemsetAsync(svec, 0, 16384, stream);
    k_cvt_x<<<dim3(64, 8, 8), 256, 0, stream>>>(x, xt_hi, xt_lo, svec);
    k_cvt_y<<<8192, 256, 0, stream>>>(y, y_bf);
    k_cvt_w<<<dim3(8, 8, 2), 256, 0, stream>>>(Wq, Wk, Wqt_hi, Wqt_lo, Wkt_hi,
                                               Wkt_lo);
    k_gram_mfma<<<dim3(8, 8, 32), 256, 0, stream>>>(xt_hi, xt_lo, G);
    k_cvt_g<<<dim3(8, 8, 8), 256, 0, stream>>>(G, Ghi, Glo);
    k_aall_mfma<<<dim3(8, 64), 256, 0, stream>>>(Wqt_hi, Wqt_lo, Ghi, Glo, Ahi,
                                                 Alo);
    k_attn3<<<dim3(8, 8), 256, 0, stream>>>(Ahi, Alo, Wqt_hi, Wqt_lo, Wkt_hi,
                                            Wkt_lo, Wv, Wp, bq, bk, bv, gm,
                                            svec, Wft, bfin);
    k_out_mfma<<<dim3(32, 64), 256, 0, stream>>>(y_bf, Wft, bfin, out);
  } else {
    float* ws = (float*)d_ws;
    float* G = ws;
    float* Aall = ws + 2097152;
    float* Wfin = ws + 4194304;
    float* bfin = ws + 6291456;
    float* svec = ws + 6295552;
    dim3 blk(16, 16);
    k_gram<<<dim3(8, 8, 8), blk, 0, stream>>>(x, G, svec);
    k_aall<<<dim3(8, 8, 8), blk, 0, stream>>>(Wq, G, Aall);
    k_attn_f32<<<dim3(8, 8), blk, 0, stream>>>(Wq, Wk, Wv, Wp, bq, bk, bv, gm,
                                               Aall, svec, Wfin, bfin);
    k_out_f32<<<dim3(64, 64), blk, 0, stream>>>(y, Wfin, bfin, out);
  }
}

// Round 4
// 357.293 us; speedup vs baseline: 2.6835x; 1.0019x over previous
//
#include <hip/hip_runtime.h>

#define B_ 8
#define K_ 4096
#define IN_ 512
#define H_ 8
#define D_ 64
#define HD_ 512  // H_*D_

typedef short bf16x8 __attribute__((ext_vector_type(8)));
typedef float f32x4 __attribute__((ext_vector_type(4)));
typedef unsigned short u16;
typedef unsigned short us8v __attribute__((ext_vector_type(8)));
typedef unsigned short us4v __attribute__((ext_vector_type(4)));

__device__ inline u16 f2bf_rn(float f) {
  unsigned u = __float_as_uint(f);
  u += 0x7fffu + ((u >> 16) & 1u);
  return (u16)(u >> 16);
}
__device__ inline float bf2f(u16 h) {
  return __uint_as_float(((unsigned)h) << 16);
}

// =========================================================================
// ws layout (bytes), fast path:
//   region0 [0, 33554432):
//     phase1: xt_hi [B][IN][K] bf16 (32MB)
//     phase2 (after k_gram): Ahi @0 (4MB), Alo @4MB, Wft @8MB (4MB)
//   xt_lo  @33554432  (32MB)
//   G      @67108864  [B][IN][IN] f32 (8MB)
//   Ghi    @75497472 (4MB)   Glo @79691776 (4MB)
//   Wqt_hi @83886080 (512KB) Wqt_lo @84410368
//   Wkt_hi @84934656         Wkt_lo @85458944
//   bfin   @85983232 (16KB)  svec @85999616 (16KB)
//   NEED = 86016000
// =========================================================================

// x (B,K,IN) f32 -> xt_hi/xt_lo (B,IN,K) bf16 split, + column sums (atomic)
__global__ __launch_bounds__(256) void k_cvt_x(const float* __restrict__ x,
                                               u16* __restrict__ xt_hi,
                                               u16* __restrict__ xt_lo,
                                               float* __restrict__ svec) {
  const int kt = blockIdx.x, ct = blockIdx.y, b = blockIdx.z;
  __shared__ float Xs[64][65];
  const int tid = threadIdx.x;
  const float* src = x + ((size_t)b * K_ + kt * 64) * IN_ + ct * 64;
#pragma unroll
  for (int r = 0; r < 4; ++r) {
    int idx = tid + 256 * r;  // 0..1023
    int k = idx >> 4, c4 = (idx & 15) * 4;
    f32x4 v = *(const f32x4*)(src + (size_t)k * IN_ + c4);
    Xs[k][c4 + 0] = v[0];
    Xs[k][c4 + 1] = v[1];
    Xs[k][c4 + 2] = v[2];
    Xs[k][c4 + 3] = v[3];
  }
  __syncthreads();
  if (tid < 64) {
    float s = 0.f;
#pragma unroll
    for (int k = 0; k < 64; ++k) s += Xs[k][tid];
    atomicAdd(&svec[b * IN_ + ct * 64 + tid], s);
  }
#pragma unroll
  for (int r = 0; r < 2; ++r) {
    int idx = tid + 256 * r;  // 0..511
    int c = idx >> 3, ck = (idx & 7) * 8;
    us8v hv, lv;
#pragma unroll
    for (int j = 0; j < 8; ++j) {
      float f = Xs[ck + j][c];
      u16 h = f2bf_rn(f);
      float lo = f - bf2f(h);
      hv[j] = h;
      lv[j] = f2bf_rn(lo);
    }
    size_t off = ((size_t)(b * IN_ + ct * 64 + c)) * K_ + kt * 64 + ck;
    *(us8v*)(xt_hi + off) = hv;
    *(us8v*)(xt_lo + off) = lv;
  }
}

// Wq/Wk (512x512) -> transposed bf16 hi/lo: Wt[dcol][c] = W[c][dcol]
__global__ __launch_bounds__(256) void k_cvt_w(
    const float* __restrict__ Wq, const float* __restrict__ Wk,
    u16* __restrict__ Wqt_hi, u16* __restrict__ Wqt_lo,
    u16* __restrict__ Wkt_hi, u16* __restrict__ Wkt_lo) {
  const int ti = blockIdx.x, tj = blockIdx.y;
  const float* src = blockIdx.z ? Wk : Wq;
  u16* dhi = blockIdx.z ? Wkt_hi : Wqt_hi;
  u16* dlo = blockIdx.z ? Wkt_lo : Wqt_lo;
  __shared__ float T[64][65];
  const int tid = threadIdx.x;
#pragma unroll
  for (int r = 0; r < 4; ++r) {
    int idx = tid + 256 * r;
    int rr = idx >> 4, c4 = (idx & 15) * 4;
    f32x4 v = *(const f32x4*)(src + (size_t)(tj * 64 + rr) * 512 + ti * 64 + c4);
    T[rr][c4 + 0] = v[0]; T[rr][c4 + 1] = v[1];
    T[rr][c4 + 2] = v[2]; T[rr][c4 + 3] = v[3];
  }
  __syncthreads();
#pragma unroll
  for (int r = 0; r < 2; ++r) {
    int idx = tid + 256 * r;
    int d = idx >> 3, ck = (idx & 7) * 8;
    us8v hv, lv;
#pragma unroll
    for (int j = 0; j < 8; ++j) {
      float f = T[ck + j][d];
      u16 h = f2bf_rn(f);
      hv[j] = h;
      lv[j] = f2bf_rn(f - bf2f(h));
    }
    size_t off = (size_t)(ti * 64 + d) * 512 + tj * 64 + ck;
    *(us8v*)(dhi + off) = hv;
    *(us8v*)(dlo + off) = lv;
  }
}

#define GP 72  // padded LDS row (64 bf16 + 8) = 144 B

// G_b += X^T X: 128x128 block tile, 2x2 waves of 64x64, bf16x3, split-K x8.
// grid: (10 upper 128-tiles, b*8+kc)
__global__ __launch_bounds__(256, 2) void k_gram_mfma(
    const u16* __restrict__ xt_hi, const u16* __restrict__ xt_lo,
    float* __restrict__ G) {
  // map pair index -> (ti,tj), ti<=tj over 4x4 tiles of 128
  int pp = blockIdx.x, ti = 0;
  while (pp >= 4 - ti) { pp -= 4 - ti; ++ti; }
  const int tj = ti + pp;
  const int b = blockIdx.y >> 3, kc = blockIdx.y & 7;
  __shared__ u16 Pih[128 * GP], Pil[128 * GP], Pjh[128 * GP], Pjl[128 * GP];
  const int tid = threadIdx.x;
  const int wave = tid >> 6, lane = tid & 63;
  const int wm = wave & 1, wn = wave >> 1;
  const int m16 = lane & 15, quad = lane >> 4;
  const size_t base_i = ((size_t)(b * IN_ + ti * 128)) * K_;
  const size_t base_j = ((size_t)(b * IN_ + tj * 128)) * K_;
  f32x4 zf = {0.f, 0.f, 0.f, 0.f};
  f32x4 acc[4][4];
#pragma unroll
  for (int mt = 0; mt < 4; ++mt)
#pragma unroll
    for (int nt = 0; nt < 4; ++nt) acc[mt][nt] = zf;
  const int kbeg = kc * 512, kend = kbeg + 512;
  for (int k0 = kbeg; k0 < kend; k0 += 64) {
    __syncthreads();
#pragma unroll
    for (int r = 0; r < 4; ++r) {
      int idx = tid + 256 * r;  // 0..1023
      int row = idx >> 3, ck = (idx & 7) * 8;
      size_t gi = base_i + (size_t)row * K_ + k0 + ck;
      size_t gj = base_j + (size_t)row * K_ + k0 + ck;
      int lo = row * GP + ck;
      *(us8v*)&Pih[lo] = *(const us8v*)(xt_hi + gi);
      *(us8v*)&Pil[lo] = *(const us8v*)(xt_lo + gi);
      *(us8v*)&Pjh[lo] = *(const us8v*)(xt_hi + gj);
      *(us8v*)&Pjl[lo] = *(const us8v*)(xt_lo + gj);
    }
    __syncthreads();
#pragma unroll
    for (int kk = 0; kk < 64; kk += 32) {
      bf16x8 ah[4], al[4], bh[4], bl[4];
#pragma unroll
      for (int t = 0; t < 4; ++t) {
        int ar = (wm * 64 + t * 16 + m16) * GP + kk + quad * 8;
        ah[t] = *(const bf16x8*)&Pih[ar];
        al[t] = *(const bf16x8*)&Pil[ar];
        int br = (wn * 64 + t * 16 + m16) * GP + kk + quad * 8;
        bh[t] = *(const bf16x8*)&Pjh[br];
        bl[t] = *(const bf16x8*)&Pjl[br];
      }
#pragma unroll
      for (int mt = 0; mt < 4; ++mt)
#pragma unroll
        for (int nt = 0; nt < 4; ++nt) {
          acc[mt][nt] = __builtin_amdgcn_mfma_f32_16x16x32_bf16(
              ah[mt], bh[nt], acc[mt][nt], 0, 0, 0);
          acc[mt][nt] = __builtin_amdgcn_mfma_f32_16x16x32_bf16(
              ah[mt], bl[nt], acc[mt][nt], 0, 0, 0);
          acc[mt][nt] = __builtin_amdgcn_mfma_f32_16x16x32_bf16(
              al[mt], bh[nt], acc[mt][nt], 0, 0, 0);
        }
    }
  }
  float* Gb = G + (size_t)b * IN_ * IN_;
#pragma unroll
  for (int mt = 0; mt < 4; ++mt)
#pragma unroll
    for (int nt = 0; nt < 4; ++nt)
#pragma unroll
      for (int r = 0; r < 4; ++r) {
        int gi = ti * 128 + wm * 64 + mt * 16 + quad * 4 + r;
        int gj = tj * 128 + wn * 64 + nt * 16 + m16;
        atomicAdd(&Gb[(size_t)gi * IN_ + gj], acc[mt][nt][r]);
      }
}

// G f32 (upper 64-tiles) -> Ghi/Glo bf16, mirroring lower tiles
__global__ __launch_bounds__(256) void k_cvt_g(const float* __restrict__ G,
                                               u16* __restrict__ Ghi,
                                               u16* __restrict__ Glo) {
  const int ti = blockIdx.x, tj = blockIdx.y, b = blockIdx.z;
  if (tj < ti) return;
  const float* Gb = G + (size_t)b * IN_ * IN_;
  u16* ghb = Ghi + (size_t)b * IN_ * IN_;
  u16* glb = Glo + (size_t)b * IN_ * IN_;
  __shared__ float T[64][65];
  const int tid = threadIdx.x;
#pragma unroll
  for (int r = 0; r < 4; ++r) {
    int idx = tid + 256 * r;
    int rr = idx >> 4, c4 = (idx & 15) * 4;
    f32x4 v = *(const f32x4*)(Gb + (size_t)(ti * 64 + rr) * IN_ + tj * 64 + c4);
    T[rr][c4 + 0] = v[0]; T[rr][c4 + 1] = v[1];
    T[rr][c4 + 2] = v[2]; T[rr][c4 + 3] = v[3];
  }
  __syncthreads();
#pragma unroll
  for (int r = 0; r < 2; ++r) {
    int idx = tid + 256 * r;
    int rr = idx >> 3, ck = (idx & 7) * 8;
    us8v hv, lv;
#pragma unroll
    for (int j = 0; j < 8; ++j) {
      float f = T[rr][ck + j];
      u16 h = f2bf_rn(f);
      hv[j] = h;
      lv[j] = f2bf_rn(f - bf2f(h));
    }
    size_t off = (size_t)(ti * 64 + rr) * IN_ + tj * 64 + ck;
    *(us8v*)(ghb + off) = hv;
    *(us8v*)(glb + off) = lv;
  }
  if (ti != tj) {
#pragma unroll
    for (int r = 0; r < 2; ++r) {
      int idx = tid + 256 * r;
      int rr = idx >> 3, ck = (idx & 7) * 8;
      us8v hv, lv;
#pragma unroll
      for (int j = 0; j < 8; ++j) {
        float f = T[ck + j][rr];  // mirrored element
        u16 h = f2bf_rn(f);
        hv[j] = h;
        lv[j] = f2bf_rn(f - bf2f(h));
      }
      size_t off = (size_t)(tj * 64 + rr) * IN_ + ti * 64 + ck;
      *(us8v*)(ghb + off) = hv;
      *(us8v*)(glb + off) = lv;
    }
  }
}

// A[hb] = Wqt_h (64x512) @ G_b (512x512), 3-product MFMA. bf16 hi/lo out.
__global__ __launch_bounds__(256) void k_aall_mfma(
    const u16* __restrict__ Wqt_hi, const u16* __restrict__ Wqt_lo,
    const u16* __restrict__ Ghi, const u16* __restrict__ Glo,
    u16* __restrict__ Ahi, u16* __restrict__ Alo) {
  const int ct = blockIdx.x;  // c' tile 0..7
  const int hb = blockIdx.y;  // h*8+b
  const int h = hb >> 3, b = hb & 7;
  __shared__ u16 S[4 * 64 * GP];
  u16* Ah = S;
  u16* Al = S + 64 * GP;
  u16* Bh = S + 2 * 64 * GP;
  u16* Bl = S + 3 * 64 * GP;
  const int tid = threadIdx.x;
  const int wave = tid >> 6, lane = tid & 63;
  const int m16 = lane & 15, quad = lane >> 4;
  const u16* Abase_h = Wqt_hi + (size_t)(h * 64) * IN_;
  const u16* Abase_l = Wqt_lo + (size_t)(h * 64) * IN_;
  const u16* Bbase_h = Ghi + (size_t)b * IN_ * IN_ + (size_t)(ct * 64) * IN_;
  const u16* Bbase_l = Glo + (size_t)b * IN_ * IN_ + (size_t)(ct * 64) * IN_;
  f32x4 zf = {0.f, 0.f, 0.f, 0.f};
  f32x4 acc[4] = {zf, zf, zf, zf};
  for (int k0 = 0; k0 < IN_; k0 += 64) {
    __syncthreads();
#pragma unroll
    for (int r = 0; r < 2; ++r) {
      int idx = tid + 256 * r;
      int row = idx >> 3, ck = (idx & 7) * 8;
      int lo = row * GP + ck;
      *(us8v*)&Ah[lo] = *(const us8v*)(Abase_h + (size_t)row * IN_ + k0 + ck);
      *(us8v*)&Al[lo] = *(const us8v*)(Abase_l + (size_t)row * IN_ + k0 + ck);
      *(us8v*)&Bh[lo] = *(const us8v*)(Bbase_h + (size_t)row * IN_ + k0 + ck);
      *(us8v*)&Bl[lo] = *(const us8v*)(Bbase_l + (size_t)row * IN_ + k0 + ck);
    }
    __syncthreads();
#pragma unroll
    for (int kk = 0; kk < 64; kk += 32) {
      int arow = (wave * 16 + m16) * GP + kk + quad * 8;
      bf16x8 ah = *(const bf16x8*)&Ah[arow];
      bf16x8 al = *(const bf16x8*)&Al[arow];
#pragma unroll
      for (int n = 0; n < 4; ++n) {
        int brow = (n * 16 + m16) * GP + kk + quad * 8;
        bf16x8 bh = *(const bf16x8*)&Bh[brow];
        bf16x8 bl = *(const bf16x8*)&Bl[brow];
        acc[n] = __builtin_amdgcn_mfma_f32_16x16x32_bf16(ah, bh, acc[n], 0, 0, 0);
        acc[n] = __builtin_amdgcn_mfma_f32_16x16x32_bf16(ah, bl, acc[n], 0, 0, 0);
        acc[n] = __builtin_amdgcn_mfma_f32_16x16x32_bf16(al, bh, acc[n], 0, 0, 0);
      }
    }
  }
  __syncthreads();
  float* Sf = (float*)S;
#pragma unroll
  for (int n = 0; n < 4; ++n)
#pragma unroll
    for (int r = 0; r < 4; ++r) {
      int d = wave * 16 + quad * 4 + r;
      int cc = n * 16 + m16;
      Sf[d * 68 + cc] = acc[n][r];
    }
  __syncthreads();
#pragma unroll
  for (int r = 0; r < 2; ++r) {
    int idx = tid + 256 * r;
    int d = idx >> 3, ck = (idx & 7) * 8;
    us8v hv, lv;
#pragma unroll
    for (int j = 0; j < 8; ++j) {
      float f = Sf[d * 68 + ck + j];
      u16 h2 = f2bf_rn(f);
      hv[j] = h2;
      lv[j] = f2bf_rn(f - bf2f(h2));
    }
    size_t off = ((size_t)hb * 64 + d) * IN_ + ct * 64 + ck;
    *(us8v*)(Ahi + off) = hv;
    *(us8v*)(Alo + off) = lv;
  }
}

// per (h,b): E = A @ Wk (MFMA 3-product) + bias, softmax, bfin,
// then Wft[q][c] = bf16((g * sum_e Wv[c,e]*attn[q,e] + Wp[c,q])/(1+g)) via MFMA
__global__ __launch_bounds__(256) void k_attn3(
    const u16* __restrict__ Ahi, const u16* __restrict__ Alo,
    const u16* __restrict__ Wqt_hi, const u16* __restrict__ Wqt_lo,
    const u16* __restrict__ Wkt_hi, const u16* __restrict__ Wkt_lo,
    const float* __restrict__ Wv, const float* __restrict__ Wp,
    const float* __restrict__ bq, const float* __restrict__ bk,
    const float* __restrict__ bv, const float* __restrict__ gamma,
    const float* __restrict__ svec, u16* __restrict__ Wft,
    float* __restrict__ bfin) {
  const int h = blockIdx.x, b = blockIdx.y;
  const int hb = h * B_ + b;
  const int tid = threadIdx.x;
  const int wave = tid >> 6, lane = tid & 63;
  const int m16 = lane & 15, quad = lane >> 4;
  __shared__ u16 S[4 * 64 * GP];
  __shared__ float Esh[64][65];
  __shared__ float t1[64], t2[64];
  u16* Ah = S;
  u16* Al = S + 64 * GP;
  u16* Bh = S + 2 * 64 * GP;
  u16* Bl = S + 3 * 64 * GP;

  if (tid < 64) {
    float s = 0.f;
    const u16* wh = Wkt_hi + (size_t)(h * 64 + tid) * IN_;
    const u16* wl = Wkt_lo + (size_t)(h * 64 + tid) * IN_;
    for (int c = 0; c < IN_; ++c)
      s += svec[b * IN_ + c] * (bf2f(wh[c]) + bf2f(wl[c]));
    t1[tid] = s;
  } else if (tid < 128) {
    int d = tid - 64;
    float s = 0.f;
    const u16* wh = Wqt_hi + (size_t)(h * 64 + d) * IN_;
    const u16* wl = Wqt_lo + (size_t)(h * 64 + d) * IN_;
    for (int c = 0; c < IN_; ++c)
      s += svec[b * IN_ + c] * (bf2f(wh[c]) + bf2f(wl[c]));
    t2[d] = s;
  }

  const u16* Abase_h = Ahi + (size_t)hb * 64 * IN_;
  const u16* Abase_l = Alo + (size_t)hb * 64 * IN_;
  const u16* Bbase_h = Wkt_hi + (size_t)(h * 64) * IN_;
  const u16* Bbase_l = Wkt_lo + (size_t)(h * 64) * IN_;
  f32x4 zf = {0.f, 0.f, 0.f, 0.f};
  f32x4 acc[4] = {zf, zf, zf, zf};
  for (int k0 = 0; k0 < IN_; k0 += 64) {
    __syncthreads();
#pragma unroll
    for (int r = 0; r < 2; ++r) {
      int idx = tid + 256 * r;
      int row = idx >> 3, ck = (idx & 7) * 8;
      int lo = row * GP + ck;
      *(us8v*)&Ah[lo] = *(const us8v*)(Abase_h + (size_t)row * IN_ + k0 + ck);
      *(us8v*)&Al[lo] = *(const us8v*)(Abase_l + (size_t)row * IN_ + k0 + ck);
      *(us8v*)&Bh[lo] = *(const us8v*)(Bbase_h + (size_t)row * IN_ + k0 + ck);
      *(us8v*)&Bl[lo] = *(const us8v*)(Bbase_l + (size_t)row * IN_ + k0 + ck);
    }
    __syncthreads();
#pragma unroll
    for (int kk = 0; kk < 64; kk += 32) {
      int arow = (wave * 16 + m16) * GP + kk + quad * 8;
      bf16x8 ah = *(const bf16x8*)&Ah[arow];
      bf16x8 al = *(const bf16x8*)&Al[arow];
#pragma unroll
      for (int n = 0; n < 4; ++n) {
        int brow = (n * 16 + m16) * GP + kk + quad * 8;
        bf16x8 bh = *(const bf16x8*)&Bh[brow];
        bf16x8 bl = *(const bf16x8*)&Bl[brow];
        acc[n] = __builtin_amdgcn_mfma_f32_16x16x32_bf16(ah, bh, acc[n], 0, 0, 0);
        acc[n] = __builtin_amdgcn_mfma_f32_16x16x32_bf16(ah, bl, acc[n], 0, 0, 0);
        acc[n] = __builtin_amdgcn_mfma_f32_16x16x32_bf16(al, bh, acc[n], 0, 0, 0);
      }
    }
  }
  __syncthreads();
#pragma unroll
  for (int n = 0; n < 4; ++n)
#pragma unroll
    for (int r = 0; r < 4; ++r) {
      int d = wave * 16 + quad * 4 + r;
      int e = n * 16 + m16;
      float bqd = bq[h * D_ + d], bke = bk[h * D_ + e];
      Esh[d][e] = acc[n][r] + bqd * t1[e] + t2[d] * bke + (float)K_ * bqd * bke;
    }
  __syncthreads();
  const float g = gamma[h];
  const float inv1g = 1.f / (1.f + g);
  if (tid < 64) {
    float m = -1e30f;
    for (int e = 0; e < 64; ++e) m = fmaxf(m, Esh[tid][e]);
    float ssum = 0.f;
    for (int e = 0; e < 64; ++e) {
      float p = __expf(Esh[tid][e] - m);
      Esh[tid][e] = p;
      ssum += p;
    }
    float inv = 1.f / ssum;
    float bsum = 0.f;
    for (int e = 0; e < 64; ++e) {
      Esh[tid][e] *= inv;
      bsum += bv[h * D_ + e] * Esh[tid][e];
    }
    bfin[hb * D_ + tid] = g * bsum * inv1g;
  }
  __syncthreads();

  bf16x8 bfr[4][2];
#pragma unroll
  for (int n = 0; n < 4; ++n)
#pragma unroll
    for (int kk = 0; kk < 2; ++kk)
#pragma unroll
      for (int j = 0; j < 8; ++j)
        bfr[n][kk][j] = f2bf_rn(Esh[n * 16 + m16][kk * 32 + quad * 8 + j]);

  u16* Wf = Wft + (size_t)hb * D_ * IN_;
#pragma unroll
  for (int mt = 0; mt < 8; ++mt) {
    f32x4 a4[4] = {zf, zf, zf, zf};
#pragma unroll
    for (int kk = 0; kk < 2; ++kk) {
      int c = wave * 128 + mt * 16 + m16;
      const float* wv = Wv + (size_t)c * HD_ + h * D_ + kk * 32 + quad * 8;
      f32x4 v0 = *(const f32x4*)wv;
      f32x4 v1 = *(const f32x4*)(wv + 4);
      bf16x8 af;
      af[0] = f2bf_rn(v0[0]); af[1] = f2bf_rn(v0[1]);
      af[2] = f2bf_rn(v0[2]); af[3] = f2bf_rn(v0[3]);
      af[4] = f2bf_rn(v1[0]); af[5] = f2bf_rn(v1[1]);
      af[6] = f2bf_rn(v1[2]); af[7] = f2bf_rn(v1[3]);
#pragma unroll
      for (int n = 0; n < 4; ++n)
        a4[n] = __builtin_amdgcn_mfma_f32_16x16x32_bf16(af, bfr[n][kk], a4[n], 0, 0, 0);
    }
    int cb = wave * 128 + mt * 16 + quad * 4;
#pragma unroll
    for (int n = 0; n < 4; ++n) {
      int q = n * 16 + m16;
      us4v st;
#pragma unroll
      for (int r = 0; r < 4; ++r) {
        float val = (g * a4[n][r] + Wp[(size_t)(cb + r) * D_ + q]) * inv1g;
        st[r] = f2bf_rn(val);
      }
      *(us4v*)(Wf + (size_t)q * IN_ + cb) = st;
    }
  }
}

// out for 4 heads: y f32 read direct as A-frags; Wft staged in LDS.
// grid (32 kt, 16): b = y&7, hq = y>>3; heads hq*4..hq*4+3
__global__ __launch_bounds__(256, 2) void k_out_mfma(
    const float* __restrict__ y, const u16* __restrict__ Wft,
    const float* __restrict__ bfin, float* __restrict__ out) {
  const int kt = blockIdx.x;
  const int b = blockIdx.y & 7, hq = blockIdx.y >> 3;
  const int h0 = hq * 4;
  __shared__ u16 Wsh[4 * 64 * GP];
  const int tid = threadIdx.x, wave = tid >> 6, lane = tid & 63;
  const int m16 = lane & 15, quad = lane >> 4;
  f32x4 zf = {0.f, 0.f, 0.f, 0.f};
  f32x4 acc[2][4][4];
#pragma unroll
  for (int ms = 0; ms < 2; ++ms)
#pragma unroll
    for (int i = 0; i < 4; ++i)
#pragma unroll
      for (int nt = 0; nt < 4; ++nt) acc[ms][i][nt] = zf;
  for (int c0 = 0; c0 < IN_; c0 += 64) {
    __syncthreads();
#pragma unroll
    for (int r = 0; r < 8; ++r) {
      int idx = tid + 256 * r;  // 0..2047
      int i = idx >> 9, q = (idx >> 3) & 63, ck = (idx & 7) * 8;
      const u16* src =
          Wft + ((size_t)((h0 + i) * 8 + b) * D_ + q) * IN_ + c0 + ck;
      *(us8v*)&Wsh[i * 64 * GP + q * GP + ck] = *(const us8v*)src;
    }
    __syncthreads();
#pragma unroll
    for (int kk = 0; kk < 2; ++kk) {
      bf16x8 af[2];
#pragma unroll
      for (int ms = 0; ms < 2; ++ms) {
        int row = kt * 128 + wave * 32 + ms * 16 + m16;
        const float* yp = y + ((size_t)b * K_ + row) * IN_ + c0 + kk * 32 + quad * 8;
        f32x4 v0 = *(const f32x4*)yp;
        f32x4 v1 = *(const f32x4*)(yp + 4);
        af[ms][0] = f2bf_rn(v0[0]); af[ms][1] = f2bf_rn(v0[1]);
        af[ms][2] = f2bf_rn(v0[2]); af[ms][3] = f2bf_rn(v0[3]);
        af[ms][4] = f2bf_rn(v1[0]); af[ms][5] = f2bf_rn(v1[1]);
        af[ms][6] = f2bf_rn(v1[2]); af[ms][7] = f2bf_rn(v1[3]);
      }
#pragma unroll
      for (int i = 0; i < 4; ++i)
#pragma unroll
        for (int nt = 0; nt < 4; ++nt) {
          bf16x8 bb = *(const bf16x8*)&Wsh[i * 64 * GP + (nt * 16 + m16) * GP +
                                           kk * 32 + quad * 8];
          acc[0][i][nt] =
              __builtin_amdgcn_mfma_f32_16x16x32_bf16(af[0], bb, acc[0][i][nt], 0, 0, 0);
          acc[1][i][nt] =
              __builtin_amdgcn_mfma_f32_16x16x32_bf16(af[1], bb, acc[1][i][nt], 0, 0, 0);
        }
    }
  }
#pragma unroll
  for (int i = 0; i < 4; ++i) {
    float* ob = out + (((size_t)b * H_ + h0 + i) * K_) * D_;
    const int hb = (h0 + i) * 8 + b;
#pragma unroll
    for (int ms = 0; ms < 2; ++ms)
#pragma unroll
      for (int nt = 0; nt < 4; ++nt) {
        int col = nt * 16 + m16;
        float bf = bfin[hb * D_ + col];
#pragma unroll
        for (int r = 0; r < 4; ++r) {
          int row = kt * 128 + wave * 32 + ms * 16 + quad * 4 + r;
          ob[(size_t)row * D_ + col] = acc[ms][i][nt][r] + bf;
        }
      }
  }
}

// =========================================================================
// Fallback f32 path (round-1 kernels), used if ws_size is too small
// =========================================================================
__global__ __launch_bounds__(256) void k_gram(const float* __restrict__ x,
                                              float* __restrict__ G,
                                              float* __restrict__ svec) {
  const int it = blockIdx.x, jt = blockIdx.y, b = blockIdx.z;
  if (jt < it) return;
  __shared__ float Xi[16][64];
  __shared__ float Xj[16][64];
  const float* Xb = x + (size_t)b * K_ * IN_;
  const int tx = threadIdx.x, ty = threadIdx.y;
  const int tid = ty * 16 + tx;
  const int i0 = it * 64, j0 = jt * 64;
  const bool diag = (it == jt);
  float acc[4][4] = {};
  float ssum = 0.f;
  for (int k0 = 0; k0 < K_; k0 += 16) {
#pragma unroll
    for (int r = 0; r < 4; ++r) {
      int idx = tid + 256 * r;
      int kk = idx >> 6, cc = idx & 63;
      const float* row = Xb + (size_t)(k0 + kk) * IN_;
      Xi[kk][cc] = row[i0 + cc];
      Xj[kk][cc] = row[j0 + cc];
    }
    __syncthreads();
#pragma unroll
    for (int kk = 0; kk < 16; ++kk) {
      float a[4], bb[4];
#pragma unroll
      for (int u = 0; u < 4; ++u) a[u] = Xi[kk][ty * 4 + u];
#pragma unroll
      for (int u = 0; u < 4; ++u) bb[u] = Xj[kk][tx * 4 + u];
#pragma unroll
      for (int u = 0; u < 4; ++u)
#pragma unroll
        for (int w = 0; w < 4; ++w) acc[u][w] += a[u] * bb[w];
    }
    if (diag && tid < 64) {
#pragma unroll
      for (int kk = 0; kk < 16; ++kk) ssum += Xi[kk][tid];
    }
    __syncthreads();
  }
  float* Gb = G + (size_t)b * IN_ * IN_;
#pragma unroll
  for (int u = 0; u < 4; ++u)
#pragma unroll
    for (int w = 0; w < 4; ++w) {
      int gi = i0 + ty * 4 + u, gj = j0 + tx * 4 + w;
      Gb[(size_t)gi * IN_ + gj] = acc[u][w];
      if (!diag) Gb[(size_t)gj * IN_ + gi] = acc[u][w];
    }
  if (diag && tid < 64) svec[b * IN_ + i0 + tid] = ssum;
}

__global__ __launch_bounds__(256) void k_aall(const float* __restrict__ Wq,
                                              const float* __restrict__ G,
                                              float* __restrict__ Aall) {
  const int jt = blockIdx.x;
  const int h = blockIdx.y, b = blockIdx.z;
  __shared__ float Ws[16][64];
  __shared__ float Gs[16][64];
  const float* Gb = G + (size_t)b * IN_ * IN_;
  const int tx = threadIdx.x, ty = threadIdx.y;
  const int tid = ty * 16 + tx;
  float acc[4][4] = {};
  for (int c0 = 0; c0 < IN_; c0 += 16) {
#pragma unroll
    for (int r = 0; r < 4; ++r) {
      int idx = tid + 256 * r;
      int kk = idx >> 6, cc = idx & 63;
      Ws[kk][cc] = Wq[(size_t)(c0 + kk) * HD_ + h * D_ + cc];
      Gs[kk][cc] = Gb[(size_t)(c0 + kk) * IN_ + jt * 64 + cc];
    }
    __syncthreads();
#pragma unroll
    for (int kk = 0; kk < 16; ++kk) {
      float a[4], bb[4];
#pragma unroll
      for (int u = 0; u < 4; ++u) a[u] = Ws[kk][ty * 4 + u];
#pragma unroll
      for (int u = 0; u < 4; ++u) bb[u] = Gs[kk][tx * 4 + u];
#pragma unroll
      for (int u = 0; u < 4; ++u)
#pragma unroll
        for (int w = 0; w < 4; ++w) acc[u][w] += a[u] * bb[w];
    }
    __syncthreads();
  }
  const int hb = h * B_ + b;
  float* Ahb = Aall + (size_t)hb * D_ * IN_;
#pragma unroll
  for (int u = 0; u < 4; ++u)
#pragma unroll
    for (int w = 0; w < 4; ++w)
      Ahb[(size_t)(ty * 4 + u) * IN_ + jt * 64 + tx * 4 + w] = acc[u][w];
}

__global__ __launch_bounds__(256) void k_attn_f32(
    const float* __restrict__ Wq, const float* __restrict__ Wk,
    const float* __restrict__ Wv, const float* __restrict__ Wp,
    const float* __restrict__ bq, const float* __restrict__ bk,
    const float* __restrict__ bv, const float* __restrict__ gamma,
    const float* __restrict__ Aall, const float* __restrict__ svec,
    float* __restrict__ Wfin, float* __restrict__ bfin) {
  const int h = blockIdx.x, b = blockIdx.y;
  const int hb = h * B_ + b;
  const int tx = threadIdx.x, ty = threadIdx.y;
  const int tid = ty * 16 + tx;
  __shared__ float Ast[64][17];
  __shared__ float Ws[16][64];
  __shared__ float Esh[64][65];
  __shared__ float t1[64], t2[64];
  const float* Ahb = Aall + (size_t)hb * D_ * IN_;
  if (tid < 64) {
    float a2 = 0.f;
    for (int c = 0; c < IN_; ++c)
      a2 += svec[b * IN_ + c] * Wk[(size_t)c * HD_ + h * D_ + tid];
    t1[tid] = a2;
  } else if (tid < 128) {
    int d = tid - 64;
    float a2 = 0.f;
    for (int c = 0; c < IN_; ++c)
      a2 += svec[b * IN_ + c] * Wq[(size_t)c * HD_ + h * D_ + d];
    t2[d] = a2;
  }
  float acc[4][4] = {};
  for (int c0 = 0; c0 < IN_; c0 += 16) {
#pragma unroll
    for (int r = 0; r < 4; ++r) {
      int idx = tid + 256 * r;
      int dd = idx >> 4, kk = idx & 15;
      Ast[dd][kk] = Ahb[(size_t)dd * IN_ + c0 + kk];
      int kk2 = idx >> 6, ee = idx & 63;
      Ws[kk2][ee] = Wk[(size_t)(c0 + kk2) * HD_ + h * D_ + ee];
    }
    __syncthreads();
#pragma unroll
    for (int kk = 0; kk < 16; ++kk) {
      float a[4], bb[4];
#pragma unroll
      for (int u = 0; u < 4; ++u) a[u] = Ast[ty * 4 + u][kk];
#pragma unroll
      for (int u = 0; u < 4; ++u) bb[u] = Ws[kk][tx * 4 + u];
#pragma unroll
      for (int u = 0; u < 4; ++u)
#pragma unroll
        for (int w = 0; w < 4; ++w) acc[u][w] += a[u] * bb[w];
    }
    __syncthreads();
  }
#pragma unroll
  for (int u = 0; u < 4; ++u) {
    int d = ty * 4 + u;
    float bqd = bq[h * D_ + d];
    float t2d = t2[d];
#pragma unroll
    for (int w = 0; w < 4; ++w) {
      int e = tx * 4 + w;
      float bke = bk[h * D_ + e];
      Esh[d][e] = acc[u][w] + bqd * t1[e] + t2d * bke + (float)K_ * bqd * bke;
    }
  }
  __syncthreads();
  if (tid < 64) {
    float m = -1e30f;
    for (int e = 0; e < 64; ++e) m = fmaxf(m, Esh[tid][e]);
    float ssum = 0.f;
    for (int e = 0; e < 64; ++e) {
      float p = __expf(Esh[tid][e] - m);
      Esh[tid][e] = p;
      ssum += p;
    }
    float inv = 1.f / ssum;
    for (int e = 0; e < 64; ++e) Esh[tid][e] *= inv;
  }
  __syncthreads();
  const float g = gamma[h];
  const float inv1g = 1.f / (1.f + g);
  if (tid < 64) {
    float a2 = 0.f;
    for (int e = 0; e < 64; ++e) a2 += bv[h * D_ + e] * Esh[tid][e];
    bfin[hb * D_ + tid] = g * a2 * inv1g;
  }
  float* Wf = Wfin + (size_t)hb * IN_ * D_;
  for (int it2 = 0; it2 < 128; ++it2) {
    int idx = tid + 256 * it2;
    int c = idx >> 6, q = idx & 63;
    const float* Wvr = Wv + (size_t)c * HD_ + h * D_;
    float a2 = 0.f;
#pragma unroll
    for (int e = 0; e < 64; ++e) a2 += Wvr[e] * Esh[q][e];
    Wf[idx] = (g * a2 + Wp[(size_t)c * D_ + q]) * inv1g;
  }
}

__global__ __launch_bounds__(256) void k_out_f32(const float* __restrict__ y,
                                                 const float* __restrict__ Wfin,
                                                 const float* __restrict__ bfin,
                                                 float* __restrict__ out) {
  const int kt = blockIdx.x;
  const int hb = blockIdx.y;
  const int h = hb >> 3, b = hb & 7;
  __shared__ float Ys[64][17];
  __shared__ float Ws[16][64];
  const int tx = threadIdx.x, ty = threadIdx.y;
  const int tid = ty * 16 + tx;
  const float* Yb = y + (size_t)b * K_ * IN_;
  const float* Wf = Wfin + (size_t)hb * IN_ * D_;
  const int k0 = kt * 64;
  float acc[4][4] = {};
  for (int c0 = 0; c0 < IN_; c0 += 16) {
#pragma unroll
    for (int r = 0; r < 4; ++r) {
      int idx = tid + 256 * r;
      int rr = idx >> 4, kk = idx & 15;
      Ys[rr][kk] = Yb[(size_t)(k0 + rr) * IN_ + c0 + kk];
      int kk2 = idx >> 6, qq = idx & 63;
      Ws[kk2][qq] = Wf[(size_t)(c0 + kk2) * D_ + qq];
    }
    __syncthreads();
#pragma unroll
    for (int kk = 0; kk < 16; ++kk) {
      float a[4], bb[4];
#pragma unroll
      for (int u = 0; u < 4; ++u) a[u] = Ys[ty * 4 + u][kk];
#pragma unroll
      for (int u = 0; u < 4; ++u) bb[u] = Ws[kk][tx * 4 + u];
#pragma unroll
      for (int u = 0; u < 4; ++u)
#pragma unroll
        for (int w = 0; w < 4; ++w) acc[u][w] += a[u] * bb[w];
    }
    __syncthreads();
  }
  float* ob = out + (((size_t)b * H_ + h) * K_ + k0) * D_;
#pragma unroll
  for (int u = 0; u < 4; ++u) {
    int k = ty * 4 + u;
#pragma unroll
    for (int w = 0; w < 4; ++w) {
      int q = tx * 4 + w;
      ob[(size_t)k * D_ + q] = acc[u][w] + bfin[hb * D_ + q];
    }
  }
}

// =========================================================================
extern "C" void kernel_launch(void* const* d_in, const int* in_sizes, int n_in,
                              void* d_out, int out_size, void* d_ws,
                              size_t ws_size, hipStream_t stream) {
  const float* x = (const float*)d_in[0];
  const float* y = (const float*)d_in[1];
  const float* Wq = (const float*)d_in[2];
  const float* bq = (const float*)d_in[3];
  const float* Wk = (const float*)d_in[4];
  const float* bk = (const float*)d_in[5];
  const float* Wv = (const float*)d_in[6];
  const float* bv = (const float*)d_in[7];
  const float* Wp = (const float*)d_in[8];
  const float* gm = (const float*)d_in[9];
  float* out = (float*)d_out;

  const size_t NEED = 86016000;
  if (ws_size >= NEED) {
    char* w = (char*)d_ws;
    u16* xt_hi = (u16*)(w);           // phase 1
    u16* Ahi = (u16*)(w);             // phase 2 aliases
    u16* Alo = (u16*)(w + 4194304);
    u16* Wft = (u16*)(w + 8388608);
    u16* xt_lo = (u16*)(w + 33554432);
    float* G = (float*)(w + 67108864);
    u16* Ghi = (u16*)(w + 75497472);
    u16* Glo = (u16*)(w + 79691776);
    u16* Wqt_hi = (u16*)(w + 83886080);
    u16* Wqt_lo = (u16*)(w + 84410368);
    u16* Wkt_hi = (u16*)(w + 84934656);
    u16* Wkt_lo = (u16*)(w + 85458944);
    float* bfin = (float*)(w + 85983232);
    float* svec = (float*)(w + 85999616);

    hipMemsetAsync(G, 0, 8388608, stream);
    hipMemsetAsync(svec, 0, 16384, stream);
    k_cvt_w<<<dim3(8, 8, 2), 256, 0, stream>>>(Wq, Wk, Wqt_hi, Wqt_lo, Wkt_hi,
                                               Wkt_lo);
    k_cvt_x<<<dim3(64, 8, 8), 256, 0, stream>>>(x, xt_hi, xt_lo, svec);
    k_gram_mfma<<<dim3(10, 64), 256, 0, stream>>>(xt_hi, xt_lo, G);
    k_cvt_g<<<dim3(8, 8, 8), 256, 0, stream>>>(G, Ghi, Glo);
    k_aall_mfma<<<dim3(8, 64), 256, 0, stream>>>(Wqt_hi, Wqt_lo, Ghi, Glo, Ahi,
                                                 Alo);
    k_attn3<<<dim3(8, 8), 256, 0, stream>>>(Ahi, Alo, Wqt_hi, Wqt_lo, Wkt_hi,
                                            Wkt_lo, Wv, Wp, bq, bk, bv, gm,
                                            svec, Wft, bfin);
    k_out_mfma<<<dim3(32, 16), 256, 0, stream>>>(y, Wft, bfin, out);
  } else {
    float* ws = (float*)d_ws;
    float* G = ws;
    float* Aall = ws + 2097152;
    float* Wfin = ws + 4194304;
    float* bfin = ws + 6291456;
    float* svec = ws + 6295552;
    dim3 blk(16, 16);
    k_gram<<<dim3(8, 8, 8), blk, 0, stream>>>(x, G, svec);
    k_aall<<<dim3(8, 8, 8), blk, 0, stream>>>(Wq, G, Aall);
    k_attn_f32<<<dim3(8, 8), blk, 0, stream>>>(Wq, Wk, Wv, Wp, bq, bk, bv, gm,
                                               Aall, svec, Wfin, bfin);
    k_out_f32<<<dim3(64, 64), blk, 0, stream>>>(y, Wfin, bfin, out);
  }
}